// Round 1
// baseline (322.591 us; speedup 1.0000x reference)
//
#include <hip/hip_runtime.h>
#include <hip/hip_bf16.h>
#include <stdint.h>

typedef __attribute__((ext_vector_type(8))) __bf16 bf16x8;
typedef __attribute__((ext_vector_type(8))) unsigned short ushort8_t;
typedef __attribute__((ext_vector_type(4))) unsigned short ushort4_t;
typedef __attribute__((ext_vector_type(4))) float f32x4;

#define MFMA16(a, b, c) __builtin_amdgcn_mfma_f32_16x16x32_bf16((a), (b), (c), 0, 0, 0)

static __device__ __forceinline__ unsigned short f2bf(float f) {
  union { float f; unsigned u; } v; v.f = f;
  unsigned r = v.u + 0x7fffu + ((v.u >> 16) & 1u);  // RNE
  return (unsigned short)(r >> 16);
}
static __device__ __forceinline__ float bf2f(unsigned short u) {
  union { unsigned u; float f; } v; v.u = ((unsigned)u) << 16; return v.f;
}

// ---------------- kernel 1: convert w_qkv f32 -> bf16 (layout [1536][256], K contiguous)
__global__ void k_convw(const float* __restrict__ w, unsigned short* __restrict__ wb) {
  int i = (blockIdx.x * 256 + threadIdx.x) * 4;  // 384 blocks * 1024 = 393216 exact
  float4 v = *(const float4*)(w + i);
  ushort4_t o = { f2bf(v.x), f2bf(v.y), f2bf(v.z), f2bf(v.w) };
  *(ushort4_t*)(wb + i) = o;
}

// ---------------- kernel 2: qkv = x @ w_qkv^T  (M=65536, N=1536, K=256), bf16 MFMA
// Block: 128 rows, full K in LDS (XOR-swizzled at 16B granularity), loop 12 n-chunks of 128.
__global__ __launch_bounds__(256) void k_gemm1(const float* __restrict__ x,
                                               const unsigned short* __restrict__ wqb,
                                               unsigned short* __restrict__ qkv) {
  __shared__ unsigned short As[128 * 256];  // [row][k], 16B chunks XOR-swizzled by row&7
  const int t = threadIdx.x;
  const long m0 = (long)blockIdx.x * 128;
  {
    const int r = t >> 1, half = t & 1;
    const float* src = x + (m0 + r) * 256 + half * 128;
#pragma unroll
    for (int j = 0; j < 32; ++j) {
      float4 v = *(const float4*)(src + 4 * j);
      int col = half * 128 + 4 * j;
      int chunk = col >> 3;                 // 8-elem (16B) chunk index
      int swz = chunk ^ (r & 7);
      unsigned short* p = &As[r * 256 + swz * 8 + (col & 7)];
      ushort4_t o = { f2bf(v.x), f2bf(v.y), f2bf(v.z), f2bf(v.w) };
      *(ushort4_t*)p = o;
    }
  }
  __syncthreads();
  const int w = t >> 6, lane = t & 63, lr = lane & 15, lg = lane >> 4;
  const int mrow0 = w * 32;  // wave owns 2 m-blocks (32 rows) x 8 n-blocks
  for (int nc = 0; nc < 12; ++nc) {
    const int e0 = nc * 128;
    f32x4 acc[2][8];
#pragma unroll
    for (int mb = 0; mb < 2; ++mb)
#pragma unroll
      for (int nb = 0; nb < 8; ++nb) acc[mb][nb] = f32x4{0.f, 0.f, 0.f, 0.f};
#pragma unroll
    for (int ks = 0; ks < 8; ++ks) {
      const int k0 = ks * 32;
      bf16x8 a[2], b[8];
#pragma unroll
      for (int mb = 0; mb < 2; ++mb) {
        int row = mrow0 + mb * 16 + lr;
        int swz = ((k0 >> 3) + lg) ^ (row & 7);
        a[mb] = *(const bf16x8*)&As[row * 256 + swz * 8];
      }
#pragma unroll
      for (int nb = 0; nb < 8; ++nb) {
        const unsigned short* p = wqb + (size_t)(e0 + nb * 16 + lr) * 256 + k0 + lg * 8;
        b[nb] = *(const bf16x8*)p;  // w row e, contiguous K: perfect B-fragment
      }
#pragma unroll
      for (int mb = 0; mb < 2; ++mb)
#pragma unroll
        for (int nb = 0; nb < 8; ++nb) acc[mb][nb] = MFMA16(a[mb], b[nb], acc[mb][nb]);
    }
#pragma unroll
    for (int mb = 0; mb < 2; ++mb)
#pragma unroll
      for (int nb = 0; nb < 8; ++nb)
#pragma unroll
        for (int rg = 0; rg < 4; ++rg) {
          long row = m0 + mrow0 + mb * 16 + lg * 4 + rg;  // C/D: col=lane&15, row=(lane>>4)*4+reg
          int e = e0 + nb * 16 + lr;
          qkv[row * 1536 + e] = f2bf(acc[mb][nb][rg]);
        }
  }
}

// ---------------- kernel 3: dots partials. Grid (64 bh, 8 chunks). Per block: 1024 n rows.
// Loads raw k,v rows (d contiguous), instance-norms per row, LDS-transposes, MFMA K^T V.
__global__ __launch_bounds__(256) void k_dots(const unsigned short* __restrict__ qkv,
                                              float* __restrict__ partials) {
  __shared__ unsigned short ktl[64 * 72];  // [d][n], stride 72 elems (16B-aligned, low-conflict)
  __shared__ unsigned short vtl[64 * 72];
  const int bh = blockIdx.x, ch = blockIdx.y;
  const int b = bh >> 3, h = bh & 7;
  const int t = threadIdx.x;
  const int w = t >> 6, lane = t & 63, lr = lane & 15, lg = lane >> 4;
  const unsigned short* kbase = qkv + ((size_t)b * 8192) * 1536 + 512 + h * 64;
  const int r = t >> 2, q4 = t & 3;  // 4 threads per n-row, 16 d-values each
  f32x4 acc[4];
#pragma unroll
  for (int eb = 0; eb < 4; ++eb) acc[eb] = f32x4{0.f, 0.f, 0.f, 0.f};
  for (int nt = 0; nt < 16; ++nt) {
    const int n0 = ch * 1024 + nt * 64;
    const unsigned short* krow = kbase + (size_t)(n0 + r) * 1536 + q4 * 16;
    ushort8_t ka = *(const ushort8_t*)krow;
    ushort8_t kb2 = *(const ushort8_t*)(krow + 8);
    ushort8_t va = *(const ushort8_t*)(krow + 512);   // v is +512 elems from k
    ushort8_t vb2 = *(const ushort8_t*)(krow + 520);
    float kf[16], vf[16];
#pragma unroll
    for (int i = 0; i < 8; ++i) {
      kf[i] = bf2f(ka[i]); kf[i + 8] = bf2f(kb2[i]);
      vf[i] = bf2f(va[i]); vf[i + 8] = bf2f(vb2[i]);
    }
    float ksum = 0, ksq = 0, vsum = 0, vsq = 0;
#pragma unroll
    for (int i = 0; i < 16; ++i) {
      ksum += kf[i]; ksq += kf[i] * kf[i];
      vsum += vf[i]; vsq += vf[i] * vf[i];
    }
    ksum += __shfl_xor(ksum, 1); ksq += __shfl_xor(ksq, 1);
    vsum += __shfl_xor(vsum, 1); vsq += __shfl_xor(vsq, 1);
    ksum += __shfl_xor(ksum, 2); ksq += __shfl_xor(ksq, 2);
    vsum += __shfl_xor(vsum, 2); vsq += __shfl_xor(vsq, 2);
    const float kmean = ksum * (1.f / 64.f);
    const float krs = rsqrtf(ksq * (1.f / 64.f) - kmean * kmean + 1e-5f);
    const float vmean = vsum * (1.f / 64.f);
    const float vrs = rsqrtf(vsq * (1.f / 64.f) - vmean * vmean + 1e-5f);
    __syncthreads();  // previous tile's fragment reads done
#pragma unroll
    for (int i = 0; i < 16; ++i) {
      int d = q4 * 16 + i;
      ktl[d * 72 + r] = f2bf((kf[i] - kmean) * krs);
      vtl[d * 72 + r] = f2bf((vf[i] - vmean) * vrs);
    }
    __syncthreads();
#pragma unroll
    for (int ns = 0; ns < 64; ns += 32) {
      bf16x8 af = *(const bf16x8*)&ktl[(16 * w + lr) * 72 + ns + lg * 8];
#pragma unroll
      for (int eb = 0; eb < 4; ++eb) {
        bf16x8 bv = *(const bf16x8*)&vtl[(16 * eb + lr) * 72 + ns + lg * 8];
        acc[eb] = MFMA16(af, bv, acc[eb]);
      }
    }
  }
  float* pb = partials + ((size_t)ch * 64 + bh) * 4096;
#pragma unroll
  for (int eb = 0; eb < 4; ++eb)
#pragma unroll
    for (int rg = 0; rg < 4; ++rg) {
      int d = 16 * w + lg * 4 + rg;
      int e = 16 * eb + lr;
      pb[d * 64 + e] = acc[eb][rg];
    }
}

// ---------------- kernel 4: M[b] = blockdiag(dots) @ w_out^T / N, bf16, B-fragment-swizzled
__global__ __launch_bounds__(256) void k_mmat(const float* __restrict__ partials,
                                              const float* __restrict__ wout,
                                              unsigned short* __restrict__ mswz) {
  __shared__ float dl[4096];
  const int bh = blockIdx.x, b = bh >> 3, h = bh & 7;
  const int t = threadIdx.x;
#pragma unroll
  for (int i = 0; i < 4; ++i) {
    int off = t * 16 + i * 4;
    f32x4 s = {0.f, 0.f, 0.f, 0.f};
    for (int c = 0; c < 8; ++c) {
      f32x4 p = *(const f32x4*)(partials + ((size_t)c * 64 + bh) * 4096 + off);
      s += p;
    }
    *(f32x4*)&dl[off] = s;
  }
  __syncthreads();
  float wrow[64];
#pragma unroll
  for (int e = 0; e < 64; e += 4) {
    f32x4 v = *(const f32x4*)(wout + (size_t)t * 512 + h * 64 + e);
    wrow[e] = v[0]; wrow[e + 1] = v[1]; wrow[e + 2] = v[2]; wrow[e + 3] = v[3];
  }
  const float scale = 1.0f / 8192.0f;
  for (int d = 0; d < 64; ++d) {
    float s = 0.f;
#pragma unroll
    for (int e = 0; e < 64; ++e) s += dl[d * 64 + e] * wrow[e];  // LDS broadcast across lanes
    s *= scale;
    int kk = h * 64 + d;
    int kblk = kk >> 5, j = kk & 7;
    int lane8 = ((kk >> 3) & 3) * 16 + (t & 15);
    int nblk = t >> 4;
    mswz[(size_t)b * 131072 + ((size_t)(kblk * 16 + nblk) * 64 + lane8) * 8 + j] = f2bf(s);
  }
}

// ---------------- kernel 5: out[b] = q[b] @ M[b] + b_out  (M=8192/b, N=256, K=512)
__global__ __launch_bounds__(512) void k_gemm2(const unsigned short* __restrict__ qkv,
                                               const unsigned short* __restrict__ mswz,
                                               const float* __restrict__ bout,
                                               float* __restrict__ out) {
  __shared__ unsigned short As[128 * 32];
  const int b = blockIdx.x >> 6, mt = blockIdx.x & 63;
  const long m0 = (long)mt * 128;
  const int t = threadIdx.x, w = t >> 6, lane = t & 63, lr = lane & 15, lg = lane >> 4;
  const unsigned short* qb = qkv + ((size_t)b * 8192 + m0) * 1536;  // q part: cols [0,512)
  const unsigned short* Mb = mswz + (size_t)b * 131072;
  const int srow = t >> 2, sq = t & 3;
  f32x4 acc[16];
#pragma unroll
  for (int nb = 0; nb < 16; ++nb) acc[nb] = f32x4{0.f, 0.f, 0.f, 0.f};
  for (int ks = 0; ks < 16; ++ks) {
    const int k0 = ks * 32;
    __syncthreads();  // previous iteration's fragment reads done
    ushort8_t sv = *(const ushort8_t*)(qb + (size_t)srow * 1536 + k0 + sq * 8);
    *(ushort8_t*)&As[srow * 32 + sq * 8] = sv;
    __syncthreads();
    bf16x8 af = *(const bf16x8*)&As[(w * 16 + lr) * 32 + lg * 8];
#pragma unroll
    for (int nb = 0; nb < 16; ++nb) {
      bf16x8 bf_ = *(const bf16x8*)(Mb + (((size_t)ks * 16 + nb) * 64 + lane) * 8);
      acc[nb] = MFMA16(af, bf_, acc[nb]);
    }
  }
  float* ob = out + ((size_t)b * 8192 + m0) * 256;
#pragma unroll
  for (int nb = 0; nb < 16; ++nb)
#pragma unroll
    for (int rg = 0; rg < 4; ++rg) {
      int row = w * 16 + lg * 4 + rg;
      int c = nb * 16 + lr;
      ob[(size_t)row * 256 + c] = acc[nb][rg] + bout[c];
    }
}

extern "C" void kernel_launch(void* const* d_in, const int* in_sizes, int n_in,
                              void* d_out, int out_size, void* d_ws, size_t ws_size,
                              hipStream_t stream) {
  const float* x    = (const float*)d_in[0];  // [8,8192,256]
  const float* wqkv = (const float*)d_in[1];  // [1536,256]
  const float* wout = (const float*)d_in[2];  // [256,512]
  const float* bout = (const float*)d_in[3];  // [256]
  float* out = (float*)d_out;                 // [8,8192,256] f32

  char* ws = (char*)d_ws;
  unsigned short* qkvb = (unsigned short*)ws;                 // 65536*1536 bf16 = 192 MB
  size_t off = (size_t)65536 * 1536 * 2;
  unsigned short* wqb = (unsigned short*)(ws + off);          // 1536*256 bf16
  off += (size_t)1536 * 256 * 2;
  float* partials = (float*)(ws + off);                       // 8*64*4096 f32 = 8 MB
  off += (size_t)8 * 64 * 4096 * 4;
  unsigned short* mswz = (unsigned short*)(ws + off);         // 8*512*256 bf16 = 2 MB
  off += (size_t)8 * 131072 * 2;

  k_convw<<<384, 256, 0, stream>>>(wqkv, wqb);
  k_gemm1<<<512, 256, 0, stream>>>(x, wqb, qkvb);
  dim3 gd(64, 8);
  k_dots<<<gd, 256, 0, stream>>>(qkvb, partials);
  k_mmat<<<64, 256, 0, stream>>>(partials, wout, mswz);
  k_gemm2<<<512, 512, 0, stream>>>(qkvb, mswz, bout, out);
}

// Round 2
// 272.254 us; speedup vs baseline: 1.1849x; 1.1849x over previous
//
#include <hip/hip_runtime.h>
#include <hip/hip_bf16.h>
#include <stdint.h>

typedef __attribute__((ext_vector_type(8))) __bf16 bf16x8;
typedef __attribute__((ext_vector_type(8))) unsigned short ushort8_t;
typedef __attribute__((ext_vector_type(4))) unsigned short ushort4_t;
typedef __attribute__((ext_vector_type(4))) float f32x4;

#define MFMA16(a, b, c) __builtin_amdgcn_mfma_f32_16x16x32_bf16((a), (b), (c), 0, 0, 0)

static __device__ __forceinline__ unsigned short f2bf(float f) {
  union { float f; unsigned u; } v; v.f = f;
  unsigned r = v.u + 0x7fffu + ((v.u >> 16) & 1u);  // RNE
  return (unsigned short)(r >> 16);
}
static __device__ __forceinline__ float bf2f(unsigned short u) {
  union { unsigned u; float f; } v; v.u = ((unsigned)u) << 16; return v.f;
}

static __device__ __forceinline__ void gld_lds16(const void* g, void* l) {
  __builtin_amdgcn_global_load_lds((const __attribute__((address_space(1))) void*)g,
                                   (__attribute__((address_space(3))) void*)l, 16, 0, 0);
}

// ---------------- kernel 1: convert w_qkv f32 -> bf16 (layout [1536][256], K contiguous)
__global__ void k_convw(const float* __restrict__ w, unsigned short* __restrict__ wb) {
  int i = (blockIdx.x * 256 + threadIdx.x) * 4;  // 384 blocks * 1024 = 393216 exact
  float4 v = *(const float4*)(w + i);
  ushort4_t o = { f2bf(v.x), f2bf(v.y), f2bf(v.z), f2bf(v.w) };
  *(ushort4_t*)(wb + i) = o;
}

// ---------------- kernel 2: qkv = x @ w_qkv^T  (M=65536, N=1536, K=256), bf16 MFMA
// v2: 128x128 tile, BK=64 double-buffered LDS, grid 512x12 blocks.
// B staged via global_load_lds (16B); A reg-staged f32->bf16 (conversion fused).
__global__ __launch_bounds__(256) void k_gemm1(const float* __restrict__ x,
                                               const unsigned short* __restrict__ wqb,
                                               unsigned short* __restrict__ qkv) {
  __shared__ unsigned short As[2][128 * 64];  // [row m][k]
  __shared__ unsigned short Bs[2][128 * 64];  // [row e][k]
  const int t = threadIdx.x;
  const int w = t >> 6, lane = t & 63, lr = lane & 15, lg = lane >> 4;
  const long m0 = (long)blockIdx.y * 128;
  const int e0 = blockIdx.x * 128;
  const int wr = w >> 1, wc = w & 1;  // wave owns 64x64 quadrant

  const int arow = t >> 4, ac4 = t & 15;       // A: f=t+i*256 -> row=f>>4, c4=f&15
  const int brow = t >> 3, bch = t & 7;        // B: idx=t+i*256 -> row=idx>>3, ch=idx&7

  float4 af[8];

  // ---- prologue: stage k0=0 into buf 0
  {
    const int k0 = 0;
#pragma unroll
    for (int i = 0; i < 4; ++i) {
      int idx = t + i * 256;
      gld_lds16(wqb + (size_t)(e0 + brow + i * 32) * 256 + k0 + bch * 8,
                &Bs[0][idx * 8]);
    }
#pragma unroll
    for (int i = 0; i < 8; ++i)
      af[i] = *(const float4*)(x + (m0 + arow + i * 16) * 256 + k0 + ac4 * 4);
#pragma unroll
    for (int i = 0; i < 8; ++i) {
      ushort4_t o = { f2bf(af[i].x), f2bf(af[i].y), f2bf(af[i].z), f2bf(af[i].w) };
      *(ushort4_t*)&As[0][(arow + i * 16) * 64 + ac4 * 4] = o;
    }
  }
  __syncthreads();

  f32x4 acc[4][4];
#pragma unroll
  for (int mb = 0; mb < 4; ++mb)
#pragma unroll
    for (int nb = 0; nb < 4; ++nb) acc[mb][nb] = f32x4{0.f, 0.f, 0.f, 0.f};

  for (int ks = 0; ks < 4; ++ks) {
    const int cur = ks & 1, nxt = cur ^ 1;
    if (ks < 3) {
      const int k0 = (ks + 1) * 64;
#pragma unroll
      for (int i = 0; i < 4; ++i) {
        int idx = t + i * 256;
        gld_lds16(wqb + (size_t)(e0 + brow + i * 32) * 256 + k0 + bch * 8,
                  &Bs[nxt][idx * 8]);
      }
#pragma unroll
      for (int i = 0; i < 8; ++i)
        af[i] = *(const float4*)(x + (m0 + arow + i * 16) * 256 + k0 + ac4 * 4);
    }
    // ---- compute on cur
#pragma unroll
    for (int kh = 0; kh < 2; ++kh) {
      bf16x8 a[4], b[4];
#pragma unroll
      for (int mb = 0; mb < 4; ++mb)
        a[mb] = *(const bf16x8*)&As[cur][(wr * 64 + mb * 16 + lr) * 64 + kh * 32 + lg * 8];
#pragma unroll
      for (int nb = 0; nb < 4; ++nb)
        b[nb] = *(const bf16x8*)&Bs[cur][(wc * 64 + nb * 16 + lr) * 64 + kh * 32 + lg * 8];
#pragma unroll
      for (int mb = 0; mb < 4; ++mb)
#pragma unroll
        for (int nb = 0; nb < 4; ++nb) acc[mb][nb] = MFMA16(a[mb], b[nb], acc[mb][nb]);
    }
    if (ks < 3) {
#pragma unroll
      for (int i = 0; i < 8; ++i) {
        ushort4_t o = { f2bf(af[i].x), f2bf(af[i].y), f2bf(af[i].z), f2bf(af[i].w) };
        *(ushort4_t*)&As[nxt][(arow + i * 16) * 64 + ac4 * 4] = o;
      }
    }
    __syncthreads();
  }

  // ---- epilogue: C write (bf16)
#pragma unroll
  for (int mb = 0; mb < 4; ++mb)
#pragma unroll
    for (int nb = 0; nb < 4; ++nb)
#pragma unroll
      for (int rg = 0; rg < 4; ++rg) {
        long row = m0 + wr * 64 + mb * 16 + lg * 4 + rg;
        int e = e0 + wc * 64 + nb * 16 + lr;
        qkv[row * 1536 + e] = f2bf(acc[mb][nb][rg]);
      }
}

// ---------------- kernel 3: dots partials. Grid (64 bh, 8 chunks). Per block: 1024 n rows.
// Loads raw k,v rows (d contiguous), instance-norms per row, LDS-transposes, MFMA K^T V.
__global__ __launch_bounds__(256) void k_dots(const unsigned short* __restrict__ qkv,
                                              float* __restrict__ partials) {
  __shared__ unsigned short ktl[64 * 72];  // [d][n], stride 72 elems
  __shared__ unsigned short vtl[64 * 72];
  const int bh = blockIdx.x, ch = blockIdx.y;
  const int b = bh >> 3, h = bh & 7;
  const int t = threadIdx.x;
  const int w = t >> 6, lane = t & 63, lr = lane & 15, lg = lane >> 4;
  const unsigned short* kbase = qkv + ((size_t)b * 8192) * 1536 + 512 + h * 64;
  const int r = t >> 2, q4 = t & 3;  // 4 threads per n-row, 16 d-values each
  f32x4 acc[4];
#pragma unroll
  for (int eb = 0; eb < 4; ++eb) acc[eb] = f32x4{0.f, 0.f, 0.f, 0.f};
  for (int nt = 0; nt < 16; ++nt) {
    const int n0 = ch * 1024 + nt * 64;
    const unsigned short* krow = kbase + (size_t)(n0 + r) * 1536 + q4 * 16;
    ushort8_t ka = *(const ushort8_t*)krow;
    ushort8_t kb2 = *(const ushort8_t*)(krow + 8);
    ushort8_t va = *(const ushort8_t*)(krow + 512);
    ushort8_t vb2 = *(const ushort8_t*)(krow + 520);
    float kf[16], vf[16];
#pragma unroll
    for (int i = 0; i < 8; ++i) {
      kf[i] = bf2f(ka[i]); kf[i + 8] = bf2f(kb2[i]);
      vf[i] = bf2f(va[i]); vf[i + 8] = bf2f(vb2[i]);
    }
    float ksum = 0, ksq = 0, vsum = 0, vsq = 0;
#pragma unroll
    for (int i = 0; i < 16; ++i) {
      ksum += kf[i]; ksq += kf[i] * kf[i];
      vsum += vf[i]; vsq += vf[i] * vf[i];
    }
    ksum += __shfl_xor(ksum, 1); ksq += __shfl_xor(ksq, 1);
    vsum += __shfl_xor(vsum, 1); vsq += __shfl_xor(vsq, 1);
    ksum += __shfl_xor(ksum, 2); ksq += __shfl_xor(ksq, 2);
    vsum += __shfl_xor(vsum, 2); vsq += __shfl_xor(vsq, 2);
    const float kmean = ksum * (1.f / 64.f);
    const float krs = rsqrtf(ksq * (1.f / 64.f) - kmean * kmean + 1e-5f);
    const float vmean = vsum * (1.f / 64.f);
    const float vrs = rsqrtf(vsq * (1.f / 64.f) - vmean * vmean + 1e-5f);
    __syncthreads();
#pragma unroll
    for (int i = 0; i < 16; ++i) {
      int d = q4 * 16 + i;
      ktl[d * 72 + r] = f2bf((kf[i] - kmean) * krs);
      vtl[d * 72 + r] = f2bf((vf[i] - vmean) * vrs);
    }
    __syncthreads();
#pragma unroll
    for (int ns = 0; ns < 64; ns += 32) {
      bf16x8 af = *(const bf16x8*)&ktl[(16 * w + lr) * 72 + ns + lg * 8];
#pragma unroll
      for (int eb = 0; eb < 4; ++eb) {
        bf16x8 bv = *(const bf16x8*)&vtl[(16 * eb + lr) * 72 + ns + lg * 8];
        acc[eb] = MFMA16(af, bv, acc[eb]);
      }
    }
  }
  float* pb = partials + ((size_t)ch * 64 + bh) * 4096;
#pragma unroll
  for (int eb = 0; eb < 4; ++eb)
#pragma unroll
    for (int rg = 0; rg < 4; ++rg) {
      int d = 16 * w + lg * 4 + rg;
      int e = 16 * eb + lr;
      pb[d * 64 + e] = acc[eb][rg];
    }
}

// ---------------- kernel 4: M[b] = blockdiag(dots) @ w_out^T / N, bf16, B-fragment-swizzled
__global__ __launch_bounds__(256) void k_mmat(const float* __restrict__ partials,
                                              const float* __restrict__ wout,
                                              unsigned short* __restrict__ mswz) {
  __shared__ float dl[4096];
  const int bh = blockIdx.x, b = bh >> 3, h = bh & 7;
  const int t = threadIdx.x;
#pragma unroll
  for (int i = 0; i < 4; ++i) {
    int off = t * 16 + i * 4;
    f32x4 s = {0.f, 0.f, 0.f, 0.f};
    for (int c = 0; c < 8; ++c) {
      f32x4 p = *(const f32x4*)(partials + ((size_t)c * 64 + bh) * 4096 + off);
      s += p;
    }
    *(f32x4*)&dl[off] = s;
  }
  __syncthreads();
  float wrow[64];
#pragma unroll
  for (int e = 0; e < 64; e += 4) {
    f32x4 v = *(const f32x4*)(wout + (size_t)t * 512 + h * 64 + e);
    wrow[e] = v[0]; wrow[e + 1] = v[1]; wrow[e + 2] = v[2]; wrow[e + 3] = v[3];
  }
  const float scale = 1.0f / 8192.0f;
  for (int d = 0; d < 64; ++d) {
    float s = 0.f;
#pragma unroll
    for (int e = 0; e < 64; ++e) s += dl[d * 64 + e] * wrow[e];
    s *= scale;
    int kk = h * 64 + d;
    int kblk = kk >> 5, j = kk & 7;
    int lane8 = ((kk >> 3) & 3) * 16 + (t & 15);
    int nblk = t >> 4;
    mswz[(size_t)b * 131072 + ((size_t)(kblk * 16 + nblk) * 64 + lane8) * 8 + j] = f2bf(s);
  }
}

// ---------------- kernel 5: out[b] = q[b] @ M[b] + b_out  (M=8192/b, N=256, K=512)
__global__ __launch_bounds__(512) void k_gemm2(const unsigned short* __restrict__ qkv,
                                               const unsigned short* __restrict__ mswz,
                                               const float* __restrict__ bout,
                                               float* __restrict__ out) {
  __shared__ unsigned short As[128 * 32];
  const int b = blockIdx.x >> 6, mt = blockIdx.x & 63;
  const long m0 = (long)mt * 128;
  const int t = threadIdx.x, w = t >> 6, lane = t & 63, lr = lane & 15, lg = lane >> 4;
  const unsigned short* qb = qkv + ((size_t)b * 8192 + m0) * 1536;
  const unsigned short* Mb = mswz + (size_t)b * 131072;
  const int srow = t >> 2, sq = t & 3;
  f32x4 acc[16];
#pragma unroll
  for (int nb = 0; nb < 16; ++nb) acc[nb] = f32x4{0.f, 0.f, 0.f, 0.f};
  for (int ks = 0; ks < 16; ++ks) {
    const int k0 = ks * 32;
    __syncthreads();
    ushort8_t sv = *(const ushort8_t*)(qb + (size_t)srow * 1536 + k0 + sq * 8);
    *(ushort8_t*)&As[srow * 32 + sq * 8] = sv;
    __syncthreads();
    bf16x8 af = *(const bf16x8*)&As[(w * 16 + lr) * 32 + lg * 8];
#pragma unroll
    for (int nb = 0; nb < 16; ++nb) {
      bf16x8 bf_ = *(const bf16x8*)(Mb + (((size_t)ks * 16 + nb) * 64 + lane) * 8);
      acc[nb] = MFMA16(af, bf_, acc[nb]);
    }
  }
  float* ob = out + ((size_t)b * 8192 + m0) * 256;
#pragma unroll
  for (int nb = 0; nb < 16; ++nb)
#pragma unroll
    for (int rg = 0; rg < 4; ++rg) {
      int row = w * 16 + lg * 4 + rg;
      int c = nb * 16 + lr;
      ob[(size_t)row * 256 + c] = acc[nb][rg] + bout[c];
    }
}

extern "C" void kernel_launch(void* const* d_in, const int* in_sizes, int n_in,
                              void* d_out, int out_size, void* d_ws, size_t ws_size,
                              hipStream_t stream) {
  const float* x    = (const float*)d_in[0];  // [8,8192,256]
  const float* wqkv = (const float*)d_in[1];  // [1536,256]
  const float* wout = (const float*)d_in[2];  // [256,512]
  const float* bout = (const float*)d_in[3];  // [256]
  float* out = (float*)d_out;                 // [8,8192,256] f32

  char* ws = (char*)d_ws;
  unsigned short* qkvb = (unsigned short*)ws;                 // 65536*1536 bf16 = 192 MB
  size_t off = (size_t)65536 * 1536 * 2;
  unsigned short* wqb = (unsigned short*)(ws + off);          // 1536*256 bf16
  off += (size_t)1536 * 256 * 2;
  float* partials = (float*)(ws + off);                       // 8*64*4096 f32 = 8 MB
  off += (size_t)8 * 64 * 4096 * 4;
  unsigned short* mswz = (unsigned short*)(ws + off);         // 8*512*256 bf16 = 2 MB
  off += (size_t)8 * 131072 * 2;

  k_convw<<<384, 256, 0, stream>>>(wqkv, wqb);
  dim3 g1(12, 512);
  k_gemm1<<<g1, 256, 0, stream>>>(x, wqb, qkvb);
  dim3 gd(64, 8);
  k_dots<<<gd, 256, 0, stream>>>(qkvb, partials);
  k_mmat<<<64, 256, 0, stream>>>(partials, wout, mswz);
  k_gemm2<<<512, 512, 0, stream>>>(qkvb, mswz, bout, out);
}

// Round 3
// 214.366 us; speedup vs baseline: 1.5049x; 1.2700x over previous
//
#include <hip/hip_runtime.h>
#include <hip/hip_bf16.h>
#include <stdint.h>

typedef __attribute__((ext_vector_type(8))) __bf16 bf16x8;
typedef __attribute__((ext_vector_type(8))) unsigned short ushort8_t;
typedef __attribute__((ext_vector_type(4))) unsigned short ushort4_t;
typedef __attribute__((ext_vector_type(4))) float f32x4;

#define MFMA16(a, b, c) __builtin_amdgcn_mfma_f32_16x16x32_bf16((a), (b), (c), 0, 0, 0)

static __device__ __forceinline__ unsigned short f2bf(float f) {
  union { float f; unsigned u; } v; v.f = f;
  unsigned r = v.u + 0x7fffu + ((v.u >> 16) & 1u);  // RNE
  return (unsigned short)(r >> 16);
}
static __device__ __forceinline__ float bf2f(unsigned short u) {
  union { unsigned u; float f; } v; v.u = ((unsigned)u) << 16; return v.f;
}

static __device__ __forceinline__ void gld_lds16(const void* g, void* l) {
  __builtin_amdgcn_global_load_lds((const __attribute__((address_space(1))) void*)g,
                                   (__attribute__((address_space(3))) void*)l, 16, 0, 0);
}

// ---------------- kernel 0: convert x f32 -> bf16 (row-major [65536][256])
__global__ __launch_bounds__(256) void k_convx(const float* __restrict__ x,
                                               unsigned short* __restrict__ xb) {
  size_t i = ((size_t)blockIdx.x * 256 + threadIdx.x) * 4;  // 16384 blocks exact
  float4 v = *(const float4*)(x + i);
  ushort4_t o = { f2bf(v.x), f2bf(v.y), f2bf(v.z), f2bf(v.w) };
  *(ushort4_t*)(xb + i) = o;
}

// ---------------- kernel 1: convert w_qkv f32 -> bf16 (layout [1536][256], K contiguous)
__global__ void k_convw(const float* __restrict__ w, unsigned short* __restrict__ wb) {
  int i = (blockIdx.x * 256 + threadIdx.x) * 4;  // 384 blocks * 1024 = 393216 exact
  float4 v = *(const float4*)(w + i);
  ushort4_t o = { f2bf(v.x), f2bf(v.y), f2bf(v.z), f2bf(v.w) };
  *(ushort4_t*)(wb + i) = o;
}

// ---------------- kernel 2: qkv = xb @ wqb^T  (M=65536, N=1536, K=256), bf16 MFMA
// 256x256 tile, BK=64, 8 waves (2Mx4N), 128KB LDS dbuf, 4-phase/K-tile interleave,
// XOR-swizzled LDS via inverse-swizzled global_load_lds source (T1+T2+T3/T4+T5).
__global__ __launch_bounds__(512) void k_gemm1(const unsigned short* __restrict__ xb,
                                               const unsigned short* __restrict__ wqb,
                                               unsigned short* __restrict__ qkv) {
  __shared__ unsigned short As[2][16384];  // [buf][(row 0..255)*64 + swz-chunk*8]
  __shared__ unsigned short Bs[2][16384];
  const int t = threadIdx.x;
  const int w = t >> 6, lane = t & 63, lr = lane & 15, lg = lane >> 4;
  const int wr = w >> 2, wc = w & 3;       // wave -> 128x64 output at (wr*128, wc*64)

  // XCD-chunked bijective swizzle: 1536 blocks, 192 per XCD
  const int id = blockIdx.x;
  const int nid = (id & 7) * 192 + (id >> 3);
  const int nt = nid % 6, mt = nid / 6;
  const long m0 = (long)mt * 256;
  const int e0 = nt * 256;

  const int srl = lane >> 3, sc = lane & 7;  // staging: lane -> row-within-8, chunk

  // ---- prologue: stage K-tile 0 (A:2 halves, B:2 halves) into buf0
#pragma unroll
  for (int i = 0; i < 2; ++i) {
    const int r = (w * 2 + i) * 8 + srl;   // 0..127 within half
    const int cs = (sc ^ (r & 7)) << 3;    // inverse-swizzled source chunk (elems)
    gld_lds16(xb + (size_t)(m0 + r) * 256 + cs,          &As[0][(w * 2 + i) * 512]);
    gld_lds16(xb + (size_t)(m0 + 128 + r) * 256 + cs,    &As[0][8192 + (w * 2 + i) * 512]);
    gld_lds16(wqb + (size_t)(e0 + r) * 256 + cs,         &Bs[0][(w * 2 + i) * 512]);
    gld_lds16(wqb + (size_t)(e0 + 128 + r) * 256 + cs,   &Bs[0][8192 + (w * 2 + i) * 512]);
  }
  __syncthreads();

  f32x4 acc[8][4];
#pragma unroll
  for (int i = 0; i < 8; ++i)
#pragma unroll
    for (int j = 0; j < 4; ++j) acc[i][j] = f32x4{0.f, 0.f, 0.f, 0.f};

  bf16x8 a[4][2], b[2][2][2];

  for (int kt = 0; kt < 4; ++kt) {
    const int cur = kt & 1, nxt = cur ^ 1;
    const int kn0 = (kt + 1) * 64;
    const bool st = kt < 3;
    const int stsw = (sc ^ (((w * 2) * 8 + srl) & 7)) << 3;  // per-lane src chunk (r%8 == lane-derived)
    // NOTE: r&7 depends only on srl (rows step by 8 per load index), so swizzle per load:
    // for load i, r = (w*2+i)*8 + srl -> r&7 == srl&7. Same for both halves.
    (void)stsw;

    // ======== phase 0: read A(qm0)+B(qn0); stage A-half0; MFMA quad(0,0)
#pragma unroll
    for (int mb = 0; mb < 4; ++mb) {
      const int R = wr * 128 + mb * 16 + lr;
#pragma unroll
      for (int kh = 0; kh < 2; ++kh)
        a[mb][kh] = *(const bf16x8*)&As[cur][R * 64 + ((((kh << 2) + lg) ^ (R & 7)) << 3)];
    }
#pragma unroll
    for (int nb = 0; nb < 2; ++nb) {
      const int E = wc * 64 + nb * 16 + lr;
#pragma unroll
      for (int kh = 0; kh < 2; ++kh)
        b[0][nb][kh] = *(const bf16x8*)&Bs[cur][E * 64 + ((((kh << 2) + lg) ^ (E & 7)) << 3)];
    }
    if (st) {
#pragma unroll
      for (int i = 0; i < 2; ++i) {
        const int r = (w * 2 + i) * 8 + srl;
        gld_lds16(xb + (size_t)(m0 + r) * 256 + kn0 + ((sc ^ (r & 7)) << 3),
                  &As[nxt][(w * 2 + i) * 512]);
      }
    }
    __builtin_amdgcn_s_barrier();
    __builtin_amdgcn_s_setprio(1);
#pragma unroll
    for (int mb = 0; mb < 4; ++mb)
#pragma unroll
      for (int nb = 0; nb < 2; ++nb)
#pragma unroll
        for (int kh = 0; kh < 2; ++kh)
          acc[mb][nb] = MFMA16(a[mb][kh], b[0][nb][kh], acc[mb][nb]);
    __builtin_amdgcn_s_setprio(0);
    __builtin_amdgcn_s_barrier();

    // ======== phase 1: read B(qn1); stage A-half1; MFMA quad(0,1)
#pragma unroll
    for (int nb = 0; nb < 2; ++nb) {
      const int E = wc * 64 + 32 + nb * 16 + lr;
#pragma unroll
      for (int kh = 0; kh < 2; ++kh)
        b[1][nb][kh] = *(const bf16x8*)&Bs[cur][E * 64 + ((((kh << 2) + lg) ^ (E & 7)) << 3)];
    }
    if (st) {
#pragma unroll
      for (int i = 0; i < 2; ++i) {
        const int r = (w * 2 + i) * 8 + srl;
        gld_lds16(xb + (size_t)(m0 + 128 + r) * 256 + kn0 + ((sc ^ (r & 7)) << 3),
                  &As[nxt][8192 + (w * 2 + i) * 512]);
      }
    }
    __builtin_amdgcn_s_barrier();
    __builtin_amdgcn_s_setprio(1);
#pragma unroll
    for (int mb = 0; mb < 4; ++mb)
#pragma unroll
      for (int nb = 0; nb < 2; ++nb)
#pragma unroll
        for (int kh = 0; kh < 2; ++kh)
          acc[mb][2 + nb] = MFMA16(a[mb][kh], b[1][nb][kh], acc[mb][2 + nb]);
    __builtin_amdgcn_s_setprio(0);
    __builtin_amdgcn_s_barrier();

    // ======== phase 2: read A(qm1); stage B-half0; MFMA quad(1,0)
#pragma unroll
    for (int mb = 0; mb < 4; ++mb) {
      const int R = wr * 128 + 64 + mb * 16 + lr;
#pragma unroll
      for (int kh = 0; kh < 2; ++kh)
        a[mb][kh] = *(const bf16x8*)&As[cur][R * 64 + ((((kh << 2) + lg) ^ (R & 7)) << 3)];
    }
    if (st) {
#pragma unroll
      for (int i = 0; i < 2; ++i) {
        const int r = (w * 2 + i) * 8 + srl;
        gld_lds16(wqb + (size_t)(e0 + r) * 256 + kn0 + ((sc ^ (r & 7)) << 3),
                  &Bs[nxt][(w * 2 + i) * 512]);
      }
    }
    __builtin_amdgcn_s_barrier();
    __builtin_amdgcn_s_setprio(1);
#pragma unroll
    for (int mb = 0; mb < 4; ++mb)
#pragma unroll
      for (int nb = 0; nb < 2; ++nb)
#pragma unroll
        for (int kh = 0; kh < 2; ++kh)
          acc[4 + mb][nb] = MFMA16(a[mb][kh], b[0][nb][kh], acc[4 + mb][nb]);
    __builtin_amdgcn_s_setprio(0);
    __builtin_amdgcn_s_barrier();

    // ======== phase 3: stage B-half1; MFMA quad(1,1); K-tile boundary drain
    if (st) {
#pragma unroll
      for (int i = 0; i < 2; ++i) {
        const int r = (w * 2 + i) * 8 + srl;
        gld_lds16(wqb + (size_t)(e0 + 128 + r) * 256 + kn0 + ((sc ^ (r & 7)) << 3),
                  &Bs[nxt][8192 + (w * 2 + i) * 512]);
      }
    }
    __builtin_amdgcn_s_barrier();
    __builtin_amdgcn_s_setprio(1);
#pragma unroll
    for (int mb = 0; mb < 4; ++mb)
#pragma unroll
      for (int nb = 0; nb < 2; ++nb)
#pragma unroll
        for (int kh = 0; kh < 2; ++kh)
          acc[4 + mb][2 + nb] = MFMA16(a[mb][kh], b[1][nb][kh], acc[4 + mb][2 + nb]);
    __builtin_amdgcn_s_setprio(0);
    __syncthreads();  // drains vmcnt(0)+lgkmcnt(0): next tile's LDS is ready
  }

  // ---- epilogue: C write (bf16). C/D: col=lane&15, row=(lane>>4)*4+reg
#pragma unroll
  for (int i = 0; i < 8; ++i) {
    const long row0 = m0 + wr * 128 + (i >> 2) * 64 + (i & 3) * 16 + lg * 4;
#pragma unroll
    for (int j = 0; j < 4; ++j) {
      const int col = e0 + wc * 64 + (j >> 1) * 32 + (j & 1) * 16 + lr;
#pragma unroll
      for (int rg = 0; rg < 4; ++rg)
        qkv[(size_t)(row0 + rg) * 1536 + col] = f2bf(acc[i][j][rg]);
    }
  }
}

// ---------------- kernel 3: dots partials. Grid (64 bh, 8 chunks). Per block: 1024 n rows.
__global__ __launch_bounds__(256) void k_dots(const unsigned short* __restrict__ qkv,
                                              float* __restrict__ partials) {
  __shared__ unsigned short ktl[64 * 72];  // [d][n], stride 72 elems
  __shared__ unsigned short vtl[64 * 72];
  const int bh = blockIdx.x, ch = blockIdx.y;
  const int b = bh >> 3, h = bh & 7;
  const int t = threadIdx.x;
  const int w = t >> 6, lane = t & 63, lr = lane & 15, lg = lane >> 4;
  const unsigned short* kbase = qkv + ((size_t)b * 8192) * 1536 + 512 + h * 64;
  const int r = t >> 2, q4 = t & 3;  // 4 threads per n-row, 16 d-values each
  f32x4 acc[4];
#pragma unroll
  for (int eb = 0; eb < 4; ++eb) acc[eb] = f32x4{0.f, 0.f, 0.f, 0.f};
  for (int nt = 0; nt < 16; ++nt) {
    const int n0 = ch * 1024 + nt * 64;
    const unsigned short* krow = kbase + (size_t)(n0 + r) * 1536 + q4 * 16;
    ushort8_t ka = *(const ushort8_t*)krow;
    ushort8_t kb2 = *(const ushort8_t*)(krow + 8);
    ushort8_t va = *(const ushort8_t*)(krow + 512);
    ushort8_t vb2 = *(const ushort8_t*)(krow + 520);
    float kf[16], vf[16];
#pragma unroll
    for (int i = 0; i < 8; ++i) {
      kf[i] = bf2f(ka[i]); kf[i + 8] = bf2f(kb2[i]);
      vf[i] = bf2f(va[i]); vf[i + 8] = bf2f(vb2[i]);
    }
    float ksum = 0, ksq = 0, vsum = 0, vsq = 0;
#pragma unroll
    for (int i = 0; i < 16; ++i) {
      ksum += kf[i]; ksq += kf[i] * kf[i];
      vsum += vf[i]; vsq += vf[i] * vf[i];
    }
    ksum += __shfl_xor(ksum, 1); ksq += __shfl_xor(ksq, 1);
    vsum += __shfl_xor(vsum, 1); vsq += __shfl_xor(vsq, 1);
    ksum += __shfl_xor(ksum, 2); ksq += __shfl_xor(ksq, 2);
    vsum += __shfl_xor(vsum, 2); vsq += __shfl_xor(vsq, 2);
    const float kmean = ksum * (1.f / 64.f);
    const float krs = rsqrtf(ksq * (1.f / 64.f) - kmean * kmean + 1e-5f);
    const float vmean = vsum * (1.f / 64.f);
    const float vrs = rsqrtf(vsq * (1.f / 64.f) - vmean * vmean + 1e-5f);
    __syncthreads();
#pragma unroll
    for (int i = 0; i < 16; ++i) {
      int d = q4 * 16 + i;
      ktl[d * 72 + r] = f2bf((kf[i] - kmean) * krs);
      vtl[d * 72 + r] = f2bf((vf[i] - vmean) * vrs);
    }
    __syncthreads();
#pragma unroll
    for (int ns = 0; ns < 64; ns += 32) {
      bf16x8 af = *(const bf16x8*)&ktl[(16 * w + lr) * 72 + ns + lg * 8];
#pragma unroll
      for (int eb = 0; eb < 4; ++eb) {
        bf16x8 bv = *(const bf16x8*)&vtl[(16 * eb + lr) * 72 + ns + lg * 8];
        acc[eb] = MFMA16(af, bv, acc[eb]);
      }
    }
  }
  float* pb = partials + ((size_t)ch * 64 + bh) * 4096;
#pragma unroll
  for (int eb = 0; eb < 4; ++eb)
#pragma unroll
    for (int rg = 0; rg < 4; ++rg) {
      int d = 16 * w + lg * 4 + rg;
      int e = 16 * eb + lr;
      pb[d * 64 + e] = acc[eb][rg];
    }
}

// ---------------- kernel 4: M[b] = blockdiag(dots) @ w_out^T / N, bf16, B-fragment-swizzled
__global__ __launch_bounds__(256) void k_mmat(const float* __restrict__ partials,
                                              const float* __restrict__ wout,
                                              unsigned short* __restrict__ mswz) {
  __shared__ float dl[4096];
  const int bh = blockIdx.x, b = bh >> 3, h = bh & 7;
  const int t = threadIdx.x;
#pragma unroll
  for (int i = 0; i < 4; ++i) {
    int off = t * 16 + i * 4;
    f32x4 s = {0.f, 0.f, 0.f, 0.f};
    for (int c = 0; c < 8; ++c) {
      f32x4 p = *(const f32x4*)(partials + ((size_t)c * 64 + bh) * 4096 + off);
      s += p;
    }
    *(f32x4*)&dl[off] = s;
  }
  __syncthreads();
  float wrow[64];
#pragma unroll
  for (int e = 0; e < 64; e += 4) {
    f32x4 v = *(const f32x4*)(wout + (size_t)t * 512 + h * 64 + e);
    wrow[e] = v[0]; wrow[e + 1] = v[1]; wrow[e + 2] = v[2]; wrow[e + 3] = v[3];
  }
  const float scale = 1.0f / 8192.0f;
  for (int d = 0; d < 64; ++d) {
    float s = 0.f;
#pragma unroll
    for (int e = 0; e < 64; ++e) s += dl[d * 64 + e] * wrow[e];
    s *= scale;
    int kk = h * 64 + d;
    int kblk = kk >> 5, j = kk & 7;
    int lane8 = ((kk >> 3) & 3) * 16 + (t & 15);
    int nblk = t >> 4;
    mswz[(size_t)b * 131072 + ((size_t)(kblk * 16 + nblk) * 64 + lane8) * 8 + j] = f2bf(s);
  }
}

// ---------------- kernel 5: out[b] = q[b] @ M[b] + b_out  (M=8192/b, N=256, K=512)
__global__ __launch_bounds__(512) void k_gemm2(const unsigned short* __restrict__ qkv,
                                               const unsigned short* __restrict__ mswz,
                                               const float* __restrict__ bout,
                                               float* __restrict__ out) {
  __shared__ unsigned short As[128 * 32];
  const int b = blockIdx.x >> 6, mt = blockIdx.x & 63;
  const long m0 = (long)mt * 128;
  const int t = threadIdx.x, w = t >> 6, lane = t & 63, lr = lane & 15, lg = lane >> 4;
  const unsigned short* qb = qkv + ((size_t)b * 8192 + m0) * 1536;
  const unsigned short* Mb = mswz + (size_t)b * 131072;
  const int srow = t >> 2, sq = t & 3;
  f32x4 acc[16];
#pragma unroll
  for (int nb = 0; nb < 16; ++nb) acc[nb] = f32x4{0.f, 0.f, 0.f, 0.f};
  for (int ks = 0; ks < 16; ++ks) {
    const int k0 = ks * 32;
    __syncthreads();
    ushort8_t sv = *(const ushort8_t*)(qb + (size_t)srow * 1536 + k0 + sq * 8);
    *(ushort8_t*)&As[srow * 32 + sq * 8] = sv;
    __syncthreads();
    bf16x8 af = *(const bf16x8*)&As[(w * 16 + lr) * 32 + lg * 8];
#pragma unroll
    for (int nb = 0; nb < 16; ++nb) {
      bf16x8 bf_ = *(const bf16x8*)(Mb + (((size_t)ks * 16 + nb) * 64 + lane) * 8);
      acc[nb] = MFMA16(af, bf_, acc[nb]);
    }
  }
  float* ob = out + ((size_t)b * 8192 + m0) * 256;
#pragma unroll
  for (int nb = 0; nb < 16; ++nb)
#pragma unroll
    for (int rg = 0; rg < 4; ++rg) {
      int row = w * 16 + lg * 4 + rg;
      int c = nb * 16 + lr;
      ob[(size_t)row * 256 + c] = acc[nb][rg] + bout[c];
    }
}

extern "C" void kernel_launch(void* const* d_in, const int* in_sizes, int n_in,
                              void* d_out, int out_size, void* d_ws, size_t ws_size,
                              hipStream_t stream) {
  const float* x    = (const float*)d_in[0];  // [8,8192,256]
  const float* wqkv = (const float*)d_in[1];  // [1536,256]
  const float* wout = (const float*)d_in[2];  // [256,512]
  const float* bout = (const float*)d_in[3];  // [256]
  float* out = (float*)d_out;                 // [8,8192,256] f32

  char* ws = (char*)d_ws;
  unsigned short* qkvb = (unsigned short*)ws;                 // 65536*1536 bf16 = 192 MB
  size_t off = (size_t)65536 * 1536 * 2;
  unsigned short* wqb = (unsigned short*)(ws + off);          // 1536*256 bf16
  off += (size_t)1536 * 256 * 2;
  float* partials = (float*)(ws + off);                       // 8*64*4096 f32 = 8 MB
  off += (size_t)8 * 64 * 4096 * 4;
  unsigned short* mswz = (unsigned short*)(ws + off);         // 8*512*256 bf16 = 2 MB
  off += (size_t)8 * 131072 * 2;
  unsigned short* xb = (unsigned short*)(ws + off);           // 65536*256 bf16 = 32 MB
  off += (size_t)65536 * 256 * 2;

  k_convx<<<16384, 256, 0, stream>>>(x, xb);
  k_convw<<<384, 256, 0, stream>>>(wqkv, wqb);
  k_gemm1<<<1536, 512, 0, stream>>>(xb, wqb, qkvb);
  dim3 gd(64, 8);
  k_dots<<<gd, 256, 0, stream>>>(qkvb, partials);
  k_mmat<<<64, 256, 0, stream>>>(partials, wout, mswz);
  k_gemm2<<<512, 512, 0, stream>>>(qkvb, mswz, bout, out);
}

// Round 4
// 195.222 us; speedup vs baseline: 1.6524x; 1.0981x over previous
//
#include <hip/hip_runtime.h>
#include <hip/hip_bf16.h>
#include <stdint.h>

typedef __attribute__((ext_vector_type(8))) __bf16 bf16x8;
typedef __attribute__((ext_vector_type(8))) unsigned short ushort8_t;
typedef __attribute__((ext_vector_type(4))) unsigned short ushort4_t;
typedef __attribute__((ext_vector_type(4))) float f32x4;

#define MFMA16(a, b, c) __builtin_amdgcn_mfma_f32_16x16x32_bf16((a), (b), (c), 0, 0, 0)

static __device__ __forceinline__ unsigned short f2bf(float f) {
  union { float f; unsigned u; } v; v.f = f;
  unsigned r = v.u + 0x7fffu + ((v.u >> 16) & 1u);  // RNE
  return (unsigned short)(r >> 16);
}
static __device__ __forceinline__ float bf2f(unsigned short u) {
  union { unsigned u; float f; } v; v.u = ((unsigned)u) << 16; return v.f;
}

static __device__ __forceinline__ void gld_lds16(const void* g, void* l) {
  __builtin_amdgcn_global_load_lds((const __attribute__((address_space(1))) void*)g,
                                   (__attribute__((address_space(3))) void*)l, 16, 0, 0);
}

// ---------------- kernel 0: convert x f32 -> bf16 (row-major [65536][256])
__global__ __launch_bounds__(256) void k_convx(const float* __restrict__ x,
                                               unsigned short* __restrict__ xb) {
  size_t i = ((size_t)blockIdx.x * 256 + threadIdx.x) * 4;  // 16384 blocks exact
  float4 v = *(const float4*)(x + i);
  ushort4_t o = { f2bf(v.x), f2bf(v.y), f2bf(v.z), f2bf(v.w) };
  *(ushort4_t*)(xb + i) = o;
}

// ---------------- kernel 1: convert w_qkv f32 -> bf16 (layout [1536][256], K contiguous)
__global__ void k_convw(const float* __restrict__ w, unsigned short* __restrict__ wb) {
  int i = (blockIdx.x * 256 + threadIdx.x) * 4;  // 384 blocks * 1024 = 393216 exact
  float4 v = *(const float4*)(w + i);
  ushort4_t o = { f2bf(v.x), f2bf(v.y), f2bf(v.z), f2bf(v.w) };
  *(ushort4_t*)(wb + i) = o;
}

// ---------------- kernel 2: qkv = xb @ wqb^T  (M=65536, N=1536, K=256), bf16 MFMA
// 256x256 tile, BK=64, 8 waves (2Mx4N), 128KB LDS dbuf, 4-phase/K-tile interleave,
// XOR-swizzled LDS via inverse-swizzled global_load_lds source (T1+T2+T3/T4+T5).
__global__ __launch_bounds__(512) void k_gemm1(const unsigned short* __restrict__ xb,
                                               const unsigned short* __restrict__ wqb,
                                               unsigned short* __restrict__ qkv) {
  __shared__ unsigned short As[2][16384];  // [buf][(row 0..255)*64 + swz-chunk*8]
  __shared__ unsigned short Bs[2][16384];
  const int t = threadIdx.x;
  const int w = t >> 6, lane = t & 63, lr = lane & 15, lg = lane >> 4;
  const int wr = w >> 2, wc = w & 3;       // wave -> 128x64 output at (wr*128, wc*64)

  // XCD-chunked bijective swizzle: 1536 blocks, 192 per XCD
  const int id = blockIdx.x;
  const int nid = (id & 7) * 192 + (id >> 3);
  const int nt = nid % 6, mt = nid / 6;
  const long m0 = (long)mt * 256;
  const int e0 = nt * 256;

  const int srl = lane >> 3, sc = lane & 7;  // staging: lane -> row-within-8, chunk

  // ---- prologue: stage K-tile 0 (A:2 halves, B:2 halves) into buf0
#pragma unroll
  for (int i = 0; i < 2; ++i) {
    const int r = (w * 2 + i) * 8 + srl;   // 0..127 within half
    const int cs = (sc ^ (r & 7)) << 3;    // inverse-swizzled source chunk (elems)
    gld_lds16(xb + (size_t)(m0 + r) * 256 + cs,          &As[0][(w * 2 + i) * 512]);
    gld_lds16(xb + (size_t)(m0 + 128 + r) * 256 + cs,    &As[0][8192 + (w * 2 + i) * 512]);
    gld_lds16(wqb + (size_t)(e0 + r) * 256 + cs,         &Bs[0][(w * 2 + i) * 512]);
    gld_lds16(wqb + (size_t)(e0 + 128 + r) * 256 + cs,   &Bs[0][8192 + (w * 2 + i) * 512]);
  }
  __syncthreads();

  f32x4 acc[8][4];
#pragma unroll
  for (int i = 0; i < 8; ++i)
#pragma unroll
    for (int j = 0; j < 4; ++j) acc[i][j] = f32x4{0.f, 0.f, 0.f, 0.f};

  bf16x8 a[4][2], b[2][2][2];

  for (int kt = 0; kt < 4; ++kt) {
    const int cur = kt & 1, nxt = cur ^ 1;
    const int kn0 = (kt + 1) * 64;
    const bool st = kt < 3;

    // ======== phase 0: read A(qm0)+B(qn0); stage A-half0; MFMA quad(0,0)
#pragma unroll
    for (int mb = 0; mb < 4; ++mb) {
      const int R = wr * 128 + mb * 16 + lr;
#pragma unroll
      for (int kh = 0; kh < 2; ++kh)
        a[mb][kh] = *(const bf16x8*)&As[cur][R * 64 + ((((kh << 2) + lg) ^ (R & 7)) << 3)];
    }
#pragma unroll
    for (int nb = 0; nb < 2; ++nb) {
      const int E = wc * 64 + nb * 16 + lr;
#pragma unroll
      for (int kh = 0; kh < 2; ++kh)
        b[0][nb][kh] = *(const bf16x8*)&Bs[cur][E * 64 + ((((kh << 2) + lg) ^ (E & 7)) << 3)];
    }
    if (st) {
#pragma unroll
      for (int i = 0; i < 2; ++i) {
        const int r = (w * 2 + i) * 8 + srl;
        gld_lds16(xb + (size_t)(m0 + r) * 256 + kn0 + ((sc ^ (r & 7)) << 3),
                  &As[nxt][(w * 2 + i) * 512]);
      }
    }
    __builtin_amdgcn_s_barrier();
    __builtin_amdgcn_s_setprio(1);
#pragma unroll
    for (int mb = 0; mb < 4; ++mb)
#pragma unroll
      for (int nb = 0; nb < 2; ++nb)
#pragma unroll
        for (int kh = 0; kh < 2; ++kh)
          acc[mb][nb] = MFMA16(a[mb][kh], b[0][nb][kh], acc[mb][nb]);
    __builtin_amdgcn_s_setprio(0);
    __builtin_amdgcn_s_barrier();

    // ======== phase 1: read B(qn1); stage A-half1; MFMA quad(0,1)
#pragma unroll
    for (int nb = 0; nb < 2; ++nb) {
      const int E = wc * 64 + 32 + nb * 16 + lr;
#pragma unroll
      for (int kh = 0; kh < 2; ++kh)
        b[1][nb][kh] = *(const bf16x8*)&Bs[cur][E * 64 + ((((kh << 2) + lg) ^ (E & 7)) << 3)];
    }
    if (st) {
#pragma unroll
      for (int i = 0; i < 2; ++i) {
        const int r = (w * 2 + i) * 8 + srl;
        gld_lds16(xb + (size_t)(m0 + 128 + r) * 256 + kn0 + ((sc ^ (r & 7)) << 3),
                  &As[nxt][8192 + (w * 2 + i) * 512]);
      }
    }
    __builtin_amdgcn_s_barrier();
    __builtin_amdgcn_s_setprio(1);
#pragma unroll
    for (int mb = 0; mb < 4; ++mb)
#pragma unroll
      for (int nb = 0; nb < 2; ++nb)
#pragma unroll
        for (int kh = 0; kh < 2; ++kh)
          acc[mb][2 + nb] = MFMA16(a[mb][kh], b[1][nb][kh], acc[mb][2 + nb]);
    __builtin_amdgcn_s_setprio(0);
    __builtin_amdgcn_s_barrier();

    // ======== phase 2: read A(qm1); stage B-half0; MFMA quad(1,0)
#pragma unroll
    for (int mb = 0; mb < 4; ++mb) {
      const int R = wr * 128 + 64 + mb * 16 + lr;
#pragma unroll
      for (int kh = 0; kh < 2; ++kh)
        a[mb][kh] = *(const bf16x8*)&As[cur][R * 64 + ((((kh << 2) + lg) ^ (R & 7)) << 3)];
    }
    if (st) {
#pragma unroll
      for (int i = 0; i < 2; ++i) {
        const int r = (w * 2 + i) * 8 + srl;
        gld_lds16(wqb + (size_t)(e0 + r) * 256 + kn0 + ((sc ^ (r & 7)) << 3),
                  &Bs[nxt][(w * 2 + i) * 512]);
      }
    }
    __builtin_amdgcn_s_barrier();
    __builtin_amdgcn_s_setprio(1);
#pragma unroll
    for (int mb = 0; mb < 4; ++mb)
#pragma unroll
      for (int nb = 0; nb < 2; ++nb)
#pragma unroll
        for (int kh = 0; kh < 2; ++kh)
          acc[4 + mb][nb] = MFMA16(a[mb][kh], b[0][nb][kh], acc[4 + mb][nb]);
    __builtin_amdgcn_s_setprio(0);
    __builtin_amdgcn_s_barrier();

    // ======== phase 3: stage B-half1; MFMA quad(1,1); K-tile boundary drain
    if (st) {
#pragma unroll
      for (int i = 0; i < 2; ++i) {
        const int r = (w * 2 + i) * 8 + srl;
        gld_lds16(wqb + (size_t)(e0 + 128 + r) * 256 + kn0 + ((sc ^ (r & 7)) << 3),
                  &Bs[nxt][8192 + (w * 2 + i) * 512]);
      }
    }
    __builtin_amdgcn_s_barrier();
    __builtin_amdgcn_s_setprio(1);
#pragma unroll
    for (int mb = 0; mb < 4; ++mb)
#pragma unroll
      for (int nb = 0; nb < 2; ++nb)
#pragma unroll
        for (int kh = 0; kh < 2; ++kh)
          acc[4 + mb][2 + nb] = MFMA16(a[mb][kh], b[1][nb][kh], acc[4 + mb][2 + nb]);
    __builtin_amdgcn_s_setprio(0);
    __syncthreads();  // drains vmcnt(0)+lgkmcnt(0): next tile's LDS is ready
  }

  // ---- epilogue: C write (bf16). C/D: col=lane&15, row=(lane>>4)*4+reg
#pragma unroll
  for (int i = 0; i < 8; ++i) {
    const long row0 = m0 + wr * 128 + (i >> 2) * 64 + (i & 3) * 16 + lg * 4;
#pragma unroll
    for (int j = 0; j < 4; ++j) {
      const int col = e0 + wc * 64 + (j >> 1) * 32 + (j & 1) * 16 + lr;
#pragma unroll
      for (int rg = 0; rg < 4; ++rg)
        qkv[(size_t)(row0 + rg) * 1536 + col] = f2bf(acc[i][j][rg]);
    }
  }
}

// ---------------- kernel 3: dots partials. Grid (64 bh, 8 chunks). Per block: 1024 n rows.
// v2: double-buffered LDS, register prefetch of next tile, ONE barrier per tile.
__global__ __launch_bounds__(256) void k_dots(const unsigned short* __restrict__ qkv,
                                              float* __restrict__ partials) {
  __shared__ unsigned short ktl[2][64 * 72];  // [buf][d][n], stride 72 elems
  __shared__ unsigned short vtl[2][64 * 72];
  const int bh = blockIdx.x, ch = blockIdx.y;
  const int b = bh >> 3, h = bh & 7;
  const int t = threadIdx.x;
  const int w = t >> 6, lane = t & 63, lr = lane & 15, lg = lane >> 4;
  const unsigned short* kbase = qkv + ((size_t)b * 8192) * 1536 + 512 + h * 64;
  const int r = t >> 2, q4 = t & 3;  // 4 threads per n-row, 16 d-values each
  const int n00 = ch * 1024;
  f32x4 acc[4];
#pragma unroll
  for (int eb = 0; eb < 4; ++eb) acc[eb] = f32x4{0.f, 0.f, 0.f, 0.f};

  ushort8_t rA[4], rB[4];
  {  // preload tile 0
    const unsigned short* krow = kbase + (size_t)(n00 + r) * 1536 + q4 * 16;
    rA[0] = *(const ushort8_t*)krow;
    rA[1] = *(const ushort8_t*)(krow + 8);
    rA[2] = *(const ushort8_t*)(krow + 512);
    rA[3] = *(const ushort8_t*)(krow + 520);
  }

#define DOTS_BODY(RC, RN, NT)                                                     \
  {                                                                               \
    float kf[16], vf[16];                                                         \
    _Pragma("unroll") for (int i = 0; i < 8; ++i) {                               \
      kf[i] = bf2f(RC[0][i]); kf[i + 8] = bf2f(RC[1][i]);                         \
      vf[i] = bf2f(RC[2][i]); vf[i + 8] = bf2f(RC[3][i]);                         \
    }                                                                             \
    float ksum = 0, ksq = 0, vsum = 0, vsq = 0;                                   \
    _Pragma("unroll") for (int i = 0; i < 16; ++i) {                              \
      ksum += kf[i]; ksq += kf[i] * kf[i];                                        \
      vsum += vf[i]; vsq += vf[i] * vf[i];                                        \
    }                                                                             \
    ksum += __shfl_xor(ksum, 1); ksq += __shfl_xor(ksq, 1);                       \
    vsum += __shfl_xor(vsum, 1); vsq += __shfl_xor(vsq, 1);                       \
    ksum += __shfl_xor(ksum, 2); ksq += __shfl_xor(ksq, 2);                       \
    vsum += __shfl_xor(vsum, 2); vsq += __shfl_xor(vsq, 2);                       \
    const float kmean = ksum * (1.f / 64.f);                                      \
    const float krs = rsqrtf(ksq * (1.f / 64.f) - kmean * kmean + 1e-5f);         \
    const float vmean = vsum * (1.f / 64.f);                                      \
    const float vrs = rsqrtf(vsq * (1.f / 64.f) - vmean * vmean + 1e-5f);         \
    const int cu = (NT) & 1;                                                      \
    _Pragma("unroll") for (int i = 0; i < 16; ++i) {                              \
      int d = q4 * 16 + i;                                                        \
      ktl[cu][d * 72 + r] = f2bf((kf[i] - kmean) * krs);                          \
      vtl[cu][d * 72 + r] = f2bf((vf[i] - vmean) * vrs);                          \
    }                                                                             \
    if ((NT) + 1 < 16) {                                                          \
      const unsigned short* krow2 =                                               \
          kbase + (size_t)(n00 + ((NT) + 1) * 64 + r) * 1536 + q4 * 16;           \
      RN[0] = *(const ushort8_t*)krow2;                                           \
      RN[1] = *(const ushort8_t*)(krow2 + 8);                                     \
      RN[2] = *(const ushort8_t*)(krow2 + 512);                                   \
      RN[3] = *(const ushort8_t*)(krow2 + 520);                                   \
    }                                                                             \
    __syncthreads();                                                              \
    _Pragma("unroll") for (int ns = 0; ns < 64; ns += 32) {                       \
      bf16x8 af = *(const bf16x8*)&ktl[cu][(16 * w + lr) * 72 + ns + lg * 8];     \
      _Pragma("unroll") for (int eb = 0; eb < 4; ++eb) {                          \
        bf16x8 bv = *(const bf16x8*)&vtl[cu][(16 * eb + lr) * 72 + ns + lg * 8];  \
        acc[eb] = MFMA16(af, bv, acc[eb]);                                        \
      }                                                                           \
    }                                                                             \
  }

  for (int nt = 0; nt < 16; nt += 2) {
    DOTS_BODY(rA, rB, nt);
    DOTS_BODY(rB, rA, nt + 1);
  }
#undef DOTS_BODY

  float* pb = partials + ((size_t)ch * 64 + bh) * 4096;
#pragma unroll
  for (int eb = 0; eb < 4; ++eb)
#pragma unroll
    for (int rg = 0; rg < 4; ++rg) {
      int d = 16 * w + lg * 4 + rg;
      int e = 16 * eb + lr;
      pb[d * 64 + e] = acc[eb][rg];
    }
}

// ---------------- kernel 4: M[b] = blockdiag(dots) @ w_out^T / N, bf16, B-fragment-swizzled
__global__ __launch_bounds__(256) void k_mmat(const float* __restrict__ partials,
                                              const float* __restrict__ wout,
                                              unsigned short* __restrict__ mswz) {
  __shared__ float dl[4096];
  const int bh = blockIdx.x, b = bh >> 3, h = bh & 7;
  const int t = threadIdx.x;
#pragma unroll
  for (int i = 0; i < 4; ++i) {
    int off = t * 16 + i * 4;
    f32x4 s = {0.f, 0.f, 0.f, 0.f};
    for (int c = 0; c < 8; ++c) {
      f32x4 p = *(const f32x4*)(partials + ((size_t)c * 64 + bh) * 4096 + off);
      s += p;
    }
    *(f32x4*)&dl[off] = s;
  }
  __syncthreads();
  float wrow[64];
#pragma unroll
  for (int e = 0; e < 64; e += 4) {
    f32x4 v = *(const f32x4*)(wout + (size_t)t * 512 + h * 64 + e);
    wrow[e] = v[0]; wrow[e + 1] = v[1]; wrow[e + 2] = v[2]; wrow[e + 3] = v[3];
  }
  const float scale = 1.0f / 8192.0f;
  for (int d = 0; d < 64; ++d) {
    float s = 0.f;
#pragma unroll
    for (int e = 0; e < 64; ++e) s += dl[d * 64 + e] * wrow[e];
    s *= scale;
    int kk = h * 64 + d;
    int kblk = kk >> 5, j = kk & 7;
    int lane8 = ((kk >> 3) & 3) * 16 + (t & 15);
    int nblk = t >> 4;
    mswz[(size_t)b * 131072 + ((size_t)(kblk * 16 + nblk) * 64 + lane8) * 8 + j] = f2bf(s);
  }
}

// ---------------- kernel 5: out[b] = q[b] @ M[b] + b_out  (M=8192/b, N=256, K=512)
// v2: 128x256 tile, BK=64 dbuf LDS via swizzled global_load_lds, 8 waves, 1 barrier/step.
__global__ __launch_bounds__(512) void k_gemm2(const unsigned short* __restrict__ qkv,
                                               const unsigned short* __restrict__ mswz,
                                               const float* __restrict__ bout,
                                               float* __restrict__ out) {
  __shared__ unsigned short As[2][128 * 64];  // 32 KB
  const int b = blockIdx.x >> 6, mt = blockIdx.x & 63;
  const long m0 = (long)mt * 128;
  const int t = threadIdx.x, w = t >> 6, lane = t & 63, lr = lane & 15, lg = lane >> 4;
  const int wr = w >> 2, wc = w & 3;  // wave: 64 rows x 64 cols
  const unsigned short* qb = qkv + ((size_t)b * 8192 + m0) * 1536;  // q cols [0,512)
  const unsigned short* Mb = mswz + (size_t)b * 131072;
  const int srl = lane >> 3, sc = lane & 7;

  // prologue: stage k-step 0
#pragma unroll
  for (int i = 0; i < 2; ++i) {
    const int row = (i * 8 + w) * 8 + srl;  // 0..127
    gld_lds16(qb + (size_t)row * 1536 + ((sc ^ (row & 7)) << 3),
              &As[0][(i * 8 + w) * 512]);
  }
  __syncthreads();

  f32x4 acc[4][4];
#pragma unroll
  for (int mb = 0; mb < 4; ++mb)
#pragma unroll
    for (int nb = 0; nb < 4; ++nb) acc[mb][nb] = f32x4{0.f, 0.f, 0.f, 0.f};

  for (int ks = 0; ks < 8; ++ks) {
    const int cur = ks & 1, nxt = cur ^ 1;
    if (ks < 7) {
      const int k0 = (ks + 1) * 64;
#pragma unroll
      for (int i = 0; i < 2; ++i) {
        const int row = (i * 8 + w) * 8 + srl;
        gld_lds16(qb + (size_t)row * 1536 + k0 + ((sc ^ (row & 7)) << 3),
                  &As[nxt][(i * 8 + w) * 512]);
      }
    }
    bf16x8 a[4][2], bfr[2][4];
#pragma unroll
    for (int mb = 0; mb < 4; ++mb) {
      const int R = wr * 64 + mb * 16 + lr;
#pragma unroll
      for (int kh = 0; kh < 2; ++kh)
        a[mb][kh] = *(const bf16x8*)&As[cur][R * 64 + ((((kh << 2) + lg) ^ (R & 7)) << 3)];
    }
#pragma unroll
    for (int kh = 0; kh < 2; ++kh)
#pragma unroll
      for (int nb = 0; nb < 4; ++nb)
        bfr[kh][nb] = *(const bf16x8*)(Mb + ((((size_t)ks * 2 + kh) * 16 + wc * 4 + nb) * 64 + lane) * 8);
#pragma unroll
    for (int mb = 0; mb < 4; ++mb)
#pragma unroll
      for (int nb = 0; nb < 4; ++nb)
#pragma unroll
        for (int kh = 0; kh < 2; ++kh)
          acc[mb][nb] = MFMA16(a[mb][kh], bfr[kh][nb], acc[mb][nb]);
    __syncthreads();  // drains vmcnt: next buffer staged; cur reads done
  }

  float bo[4];
#pragma unroll
  for (int nb = 0; nb < 4; ++nb) bo[nb] = bout[wc * 64 + nb * 16 + lr];
  float* ob = out + ((size_t)b * 8192 + m0) * 256;
#pragma unroll
  for (int mb = 0; mb < 4; ++mb)
#pragma unroll
    for (int nb = 0; nb < 4; ++nb)
#pragma unroll
      for (int rg = 0; rg < 4; ++rg) {
        int row = wr * 64 + mb * 16 + lg * 4 + rg;
        int c = wc * 64 + nb * 16 + lr;
        ob[(size_t)row * 256 + c] = acc[mb][nb][rg] + bo[nb];
      }
}

extern "C" void kernel_launch(void* const* d_in, const int* in_sizes, int n_in,
                              void* d_out, int out_size, void* d_ws, size_t ws_size,
                              hipStream_t stream) {
  const float* x    = (const float*)d_in[0];  // [8,8192,256]
  const float* wqkv = (const float*)d_in[1];  // [1536,256]
  const float* wout = (const float*)d_in[2];  // [256,512]
  const float* bout = (const float*)d_in[3];  // [256]
  float* out = (float*)d_out;                 // [8,8192,256] f32

  char* ws = (char*)d_ws;
  unsigned short* qkvb = (unsigned short*)ws;                 // 65536*1536 bf16 = 192 MB
  size_t off = (size_t)65536 * 1536 * 2;
  unsigned short* wqb = (unsigned short*)(ws + off);          // 1536*256 bf16
  off += (size_t)1536 * 256 * 2;
  float* partials = (float*)(ws + off);                       // 8*64*4096 f32 = 8 MB
  off += (size_t)8 * 64 * 4096 * 4;
  unsigned short* mswz = (unsigned short*)(ws + off);         // 8*512*256 bf16 = 2 MB
  off += (size_t)8 * 131072 * 2;
  unsigned short* xb = (unsigned short*)(ws + off);           // 65536*256 bf16 = 32 MB
  off += (size_t)65536 * 256 * 2;

  k_convx<<<16384, 256, 0, stream>>>(x, xb);
  k_convw<<<384, 256, 0, stream>>>(wqkv, wqb);
  k_gemm1<<<1536, 512, 0, stream>>>(xb, wqb, qkvb);
  dim3 gd(64, 8);
  k_dots<<<gd, 256, 0, stream>>>(qkvb, partials);
  k_mmat<<<64, 256, 0, stream>>>(partials, wout, mswz);
  k_gemm2<<<512, 512, 0, stream>>>(qkvb, mswz, bout, out);
}

// Round 5
// 183.868 us; speedup vs baseline: 1.7545x; 1.0617x over previous
//
#include <hip/hip_runtime.h>
#include <hip/hip_bf16.h>
#include <stdint.h>

typedef __attribute__((ext_vector_type(8))) __bf16 bf16x8;
typedef __attribute__((ext_vector_type(8))) unsigned short ushort8_t;
typedef __attribute__((ext_vector_type(4))) unsigned short ushort4_t;
typedef __attribute__((ext_vector_type(4))) float f32x4;

#define MFMA16(a, b, c) __builtin_amdgcn_mfma_f32_16x16x32_bf16((a), (b), (c), 0, 0, 0)

static __device__ __forceinline__ unsigned short f2bf(float f) {
  union { float f; unsigned u; } v; v.f = f;
  unsigned r = v.u + 0x7fffu + ((v.u >> 16) & 1u);  // RNE
  return (unsigned short)(r >> 16);
}
static __device__ __forceinline__ float bf2f(unsigned short u) {
  union { unsigned u; float f; } v; v.u = ((unsigned)u) << 16; return v.f;
}

static __device__ __forceinline__ void gld_lds16(const void* g, void* l) {
  __builtin_amdgcn_global_load_lds((const __attribute__((address_space(1))) void*)g,
                                   (__attribute__((address_space(3))) void*)l, 16, 0, 0);
}

// ---------------- kernel 0a: convert x f32 -> bf16 (row-major [65536][256])
__global__ __launch_bounds__(256) void k_convx(const float* __restrict__ x,
                                               unsigned short* __restrict__ xb) {
  size_t i = ((size_t)blockIdx.x * 256 + threadIdx.x) * 4;  // 16384 blocks exact
  float4 v = *(const float4*)(x + i);
  ushort4_t o = { f2bf(v.x), f2bf(v.y), f2bf(v.z), f2bf(v.w) };
  *(ushort4_t*)(xb + i) = o;
}

// ---------------- kernel 0b: convert w_qkv f32 -> bf16 ([1536][256])
__global__ void k_convw(const float* __restrict__ w, unsigned short* __restrict__ wb) {
  int i = (blockIdx.x * 256 + threadIdx.x) * 4;  // 384 blocks
  float4 v = *(const float4*)(w + i);
  ushort4_t o = { f2bf(v.x), f2bf(v.y), f2bf(v.z), f2bf(v.w) };
  *(ushort4_t*)(wb + i) = o;
}

// ---------------- kernel 0c: convert w_out f32 -> bf16 ([256][512])
__global__ void k_convo(const float* __restrict__ w, unsigned short* __restrict__ wb) {
  int i = (blockIdx.x * 256 + threadIdx.x) * 4;  // 128 blocks
  float4 v = *(const float4*)(w + i);
  ushort4_t o = { f2bf(v.x), f2bf(v.y), f2bf(v.z), f2bf(v.w) };
  *(ushort4_t*)(wb + i) = o;
}

// ---------------- kernel 1: kv = xb @ w_kv^T  (M=65536, N=1024 [K|V cols], K=256)
// 256x256 tile, BK=64, 8 waves, 128KB LDS dbuf, 4-phase/K-tile (T1+T2+T3/T4+T5).
__global__ __launch_bounds__(512) void k_gemm1(const unsigned short* __restrict__ xb,
                                               const unsigned short* __restrict__ wqb,
                                               unsigned short* __restrict__ kvb) {
  __shared__ unsigned short As[2][16384];  // [buf][(row 0..255)*64 + swz-chunk*8]
  __shared__ unsigned short Bs[2][16384];
  const int t = threadIdx.x;
  const int w = t >> 6, lane = t & 63, lr = lane & 15, lg = lane >> 4;
  const int wr = w >> 2, wc = w & 3;       // wave -> 128x64 output at (wr*128, wc*64)

  // XCD-chunked bijective swizzle: 1024 blocks, 128 per XCD
  const int id = blockIdx.x;
  const int nid = (id & 7) * 128 + (id >> 3);
  const int nt = nid & 3, mt = nid >> 2;
  const long m0 = (long)mt * 256;
  const int e0 = 512 + nt * 256;           // w_qkv rows for K,V only

  const int srl = lane >> 3, sc = lane & 7;

  // ---- prologue: stage K-tile 0
#pragma unroll
  for (int i = 0; i < 2; ++i) {
    const int r = (w * 2 + i) * 8 + srl;
    const int cs = (sc ^ (r & 7)) << 3;
    gld_lds16(xb + (size_t)(m0 + r) * 256 + cs,          &As[0][(w * 2 + i) * 512]);
    gld_lds16(xb + (size_t)(m0 + 128 + r) * 256 + cs,    &As[0][8192 + (w * 2 + i) * 512]);
    gld_lds16(wqb + (size_t)(e0 + r) * 256 + cs,         &Bs[0][(w * 2 + i) * 512]);
    gld_lds16(wqb + (size_t)(e0 + 128 + r) * 256 + cs,   &Bs[0][8192 + (w * 2 + i) * 512]);
  }
  __syncthreads();

  f32x4 acc[8][4];
#pragma unroll
  for (int i = 0; i < 8; ++i)
#pragma unroll
    for (int j = 0; j < 4; ++j) acc[i][j] = f32x4{0.f, 0.f, 0.f, 0.f};

  bf16x8 a[4][2], b[2][2][2];

  for (int kt = 0; kt < 4; ++kt) {
    const int cur = kt & 1, nxt = cur ^ 1;
    const int kn0 = (kt + 1) * 64;
    const bool st = kt < 3;

    // phase 0: read A(qm0)+B(qn0); stage A-half0; MFMA quad(0,0)
#pragma unroll
    for (int mb = 0; mb < 4; ++mb) {
      const int R = wr * 128 + mb * 16 + lr;
#pragma unroll
      for (int kh = 0; kh < 2; ++kh)
        a[mb][kh] = *(const bf16x8*)&As[cur][R * 64 + ((((kh << 2) + lg) ^ (R & 7)) << 3)];
    }
#pragma unroll
    for (int nb = 0; nb < 2; ++nb) {
      const int E = wc * 64 + nb * 16 + lr;
#pragma unroll
      for (int kh = 0; kh < 2; ++kh)
        b[0][nb][kh] = *(const bf16x8*)&Bs[cur][E * 64 + ((((kh << 2) + lg) ^ (E & 7)) << 3)];
    }
    if (st) {
#pragma unroll
      for (int i = 0; i < 2; ++i) {
        const int r = (w * 2 + i) * 8 + srl;
        gld_lds16(xb + (size_t)(m0 + r) * 256 + kn0 + ((sc ^ (r & 7)) << 3),
                  &As[nxt][(w * 2 + i) * 512]);
      }
    }
    __builtin_amdgcn_s_barrier();
    __builtin_amdgcn_s_setprio(1);
#pragma unroll
    for (int mb = 0; mb < 4; ++mb)
#pragma unroll
      for (int nb = 0; nb < 2; ++nb)
#pragma unroll
        for (int kh = 0; kh < 2; ++kh)
          acc[mb][nb] = MFMA16(a[mb][kh], b[0][nb][kh], acc[mb][nb]);
    __builtin_amdgcn_s_setprio(0);
    __builtin_amdgcn_s_barrier();

    // phase 1: read B(qn1); stage A-half1; MFMA quad(0,1)
#pragma unroll
    for (int nb = 0; nb < 2; ++nb) {
      const int E = wc * 64 + 32 + nb * 16 + lr;
#pragma unroll
      for (int kh = 0; kh < 2; ++kh)
        b[1][nb][kh] = *(const bf16x8*)&Bs[cur][E * 64 + ((((kh << 2) + lg) ^ (E & 7)) << 3)];
    }
    if (st) {
#pragma unroll
      for (int i = 0; i < 2; ++i) {
        const int r = (w * 2 + i) * 8 + srl;
        gld_lds16(xb + (size_t)(m0 + 128 + r) * 256 + kn0 + ((sc ^ (r & 7)) << 3),
                  &As[nxt][8192 + (w * 2 + i) * 512]);
      }
    }
    __builtin_amdgcn_s_barrier();
    __builtin_amdgcn_s_setprio(1);
#pragma unroll
    for (int mb = 0; mb < 4; ++mb)
#pragma unroll
      for (int nb = 0; nb < 2; ++nb)
#pragma unroll
        for (int kh = 0; kh < 2; ++kh)
          acc[mb][2 + nb] = MFMA16(a[mb][kh], b[1][nb][kh], acc[mb][2 + nb]);
    __builtin_amdgcn_s_setprio(0);
    __builtin_amdgcn_s_barrier();

    // phase 2: read A(qm1); stage B-half0; MFMA quad(1,0)
#pragma unroll
    for (int mb = 0; mb < 4; ++mb) {
      const int R = wr * 128 + 64 + mb * 16 + lr;
#pragma unroll
      for (int kh = 0; kh < 2; ++kh)
        a[mb][kh] = *(const bf16x8*)&As[cur][R * 64 + ((((kh << 2) + lg) ^ (R & 7)) << 3)];
    }
    if (st) {
#pragma unroll
      for (int i = 0; i < 2; ++i) {
        const int r = (w * 2 + i) * 8 + srl;
        gld_lds16(wqb + (size_t)(e0 + r) * 256 + kn0 + ((sc ^ (r & 7)) << 3),
                  &Bs[nxt][(w * 2 + i) * 512]);
      }
    }
    __builtin_amdgcn_s_barrier();
    __builtin_amdgcn_s_setprio(1);
#pragma unroll
    for (int mb = 0; mb < 4; ++mb)
#pragma unroll
      for (int nb = 0; nb < 2; ++nb)
#pragma unroll
        for (int kh = 0; kh < 2; ++kh)
          acc[4 + mb][nb] = MFMA16(a[mb][kh], b[0][nb][kh], acc[4 + mb][nb]);
    __builtin_amdgcn_s_setprio(0);
    __builtin_amdgcn_s_barrier();

    // phase 3: stage B-half1; MFMA quad(1,1); K-tile boundary drain
    if (st) {
#pragma unroll
      for (int i = 0; i < 2; ++i) {
        const int r = (w * 2 + i) * 8 + srl;
        gld_lds16(wqb + (size_t)(e0 + 128 + r) * 256 + kn0 + ((sc ^ (r & 7)) << 3),
                  &Bs[nxt][8192 + (w * 2 + i) * 512]);
      }
    }
    __builtin_amdgcn_s_barrier();
    __builtin_amdgcn_s_setprio(1);
#pragma unroll
    for (int mb = 0; mb < 4; ++mb)
#pragma unroll
      for (int nb = 0; nb < 2; ++nb)
#pragma unroll
        for (int kh = 0; kh < 2; ++kh)
          acc[4 + mb][2 + nb] = MFMA16(a[mb][kh], b[1][nb][kh], acc[4 + mb][2 + nb]);
    __builtin_amdgcn_s_setprio(0);
    __syncthreads();
  }

  // ---- epilogue: write kv (bf16), row stride 1024
#pragma unroll
  for (int i = 0; i < 8; ++i) {
    const long row0 = m0 + wr * 128 + (i >> 2) * 64 + (i & 3) * 16 + lg * 4;
#pragma unroll
    for (int j = 0; j < 4; ++j) {
      const int col = nt * 256 + wc * 64 + (j >> 1) * 32 + (j & 1) * 16 + lr;
#pragma unroll
      for (int rg = 0; rg < 4; ++rg)
        kvb[(size_t)(row0 + rg) * 1024 + col] = f2bf(acc[i][j][rg]);
    }
  }
}

// ---------------- kernel 3: dots partials. Grid (64 bh, 8 chunks). kv stride 1024.
__global__ __launch_bounds__(256) void k_dots(const unsigned short* __restrict__ kvb,
                                              float* __restrict__ partials) {
  __shared__ unsigned short ktl[2][64 * 72];
  __shared__ unsigned short vtl[2][64 * 72];
  const int bh = blockIdx.x, ch = blockIdx.y;
  const int b = bh >> 3, h = bh & 7;
  const int t = threadIdx.x;
  const int w = t >> 6, lane = t & 63, lr = lane & 15, lg = lane >> 4;
  const unsigned short* kbase = kvb + ((size_t)b * 8192) * 1024 + h * 64;
  const int r = t >> 2, q4 = t & 3;
  const int n00 = ch * 1024;
  f32x4 acc[4];
#pragma unroll
  for (int eb = 0; eb < 4; ++eb) acc[eb] = f32x4{0.f, 0.f, 0.f, 0.f};

  ushort8_t rA[4], rB[4];
  {
    const unsigned short* krow = kbase + (size_t)(n00 + r) * 1024 + q4 * 16;
    rA[0] = *(const ushort8_t*)krow;
    rA[1] = *(const ushort8_t*)(krow + 8);
    rA[2] = *(const ushort8_t*)(krow + 512);
    rA[3] = *(const ushort8_t*)(krow + 520);
  }

#define DOTS_BODY(RC, RN, NT)                                                     \
  {                                                                               \
    float kf[16], vf[16];                                                         \
    _Pragma("unroll") for (int i = 0; i < 8; ++i) {                               \
      kf[i] = bf2f(RC[0][i]); kf[i + 8] = bf2f(RC[1][i]);                         \
      vf[i] = bf2f(RC[2][i]); vf[i + 8] = bf2f(RC[3][i]);                         \
    }                                                                             \
    float ksum = 0, ksq = 0, vsum = 0, vsq = 0;                                   \
    _Pragma("unroll") for (int i = 0; i < 16; ++i) {                              \
      ksum += kf[i]; ksq += kf[i] * kf[i];                                        \
      vsum += vf[i]; vsq += vf[i] * vf[i];                                        \
    }                                                                             \
    ksum += __shfl_xor(ksum, 1); ksq += __shfl_xor(ksq, 1);                       \
    vsum += __shfl_xor(vsum, 1); vsq += __shfl_xor(vsq, 1);                       \
    ksum += __shfl_xor(ksum, 2); ksq += __shfl_xor(ksq, 2);                       \
    vsum += __shfl_xor(vsum, 2); vsq += __shfl_xor(vsq, 2);                       \
    const float kmean = ksum * (1.f / 64.f);                                      \
    const float krs = rsqrtf(ksq * (1.f / 64.f) - kmean * kmean + 1e-5f);         \
    const float vmean = vsum * (1.f / 64.f);                                      \
    const float vrs = rsqrtf(vsq * (1.f / 64.f) - vmean * vmean + 1e-5f);         \
    const int cu = (NT) & 1;                                                      \
    _Pragma("unroll") for (int i = 0; i < 16; ++i) {                              \
      int d = q4 * 16 + i;                                                        \
      ktl[cu][d * 72 + r] = f2bf((kf[i] - kmean) * krs);                          \
      vtl[cu][d * 72 + r] = f2bf((vf[i] - vmean) * vrs);                          \
    }                                                                             \
    if ((NT) + 1 < 16) {                                                          \
      const unsigned short* krow2 =                                               \
          kbase + (size_t)(n00 + ((NT) + 1) * 64 + r) * 1024 + q4 * 16;           \
      RN[0] = *(const ushort8_t*)krow2;                                           \
      RN[1] = *(const ushort8_t*)(krow2 + 8);                                     \
      RN[2] = *(const ushort8_t*)(krow2 + 512);                                   \
      RN[3] = *(const ushort8_t*)(krow2 + 520);                                   \
    }                                                                             \
    __syncthreads();                                                              \
    _Pragma("unroll") for (int ns = 0; ns < 64; ns += 32) {                       \
      bf16x8 af = *(const bf16x8*)&ktl[cu][(16 * w + lr) * 72 + ns + lg * 8];     \
      _Pragma("unroll") for (int eb = 0; eb < 4; ++eb) {                          \
        bf16x8 bv = *(const bf16x8*)&vtl[cu][(16 * eb + lr) * 72 + ns + lg * 8];  \
        acc[eb] = MFMA16(af, bv, acc[eb]);                                        \
      }                                                                           \
    }                                                                             \
  }

  for (int nt = 0; nt < 16; nt += 2) {
    DOTS_BODY(rA, rB, nt);
    DOTS_BODY(rB, rA, nt + 1);
  }
#undef DOTS_BODY

  float* pb = partials + ((size_t)ch * 64 + bh) * 4096;
#pragma unroll
  for (int eb = 0; eb < 4; ++eb)
#pragma unroll
    for (int rg = 0; rg < 4; ++rg) {
      int d = 16 * w + lg * 4 + rg;
      int e = 16 * eb + lr;
      pb[d * 64 + e] = acc[eb][rg];
    }
}

// ---------------- kernel 4: tmpT[b][k][h*64+e] = (1/N) * sum_d dots_h[d,e] * Wq[h*64+d, k]
// One block per bh. f32 math, bf16 store.
__global__ __launch_bounds__(256) void k_mmat(const float* __restrict__ partials,
                                              const float* __restrict__ wqkv,
                                              unsigned short* __restrict__ tmpT) {
  __shared__ float dl[4096];        // dots [d][e]
  __shared__ float wqls[64 * 256];  // Wq rows h*64+d: [d][k]
  const int bh = blockIdx.x, b = bh >> 3, h = bh & 7;
  const int t = threadIdx.x;
#pragma unroll
  for (int i = 0; i < 4; ++i) {
    int off = t * 16 + i * 4;
    f32x4 s = {0.f, 0.f, 0.f, 0.f};
    for (int c = 0; c < 8; ++c) {
      f32x4 p = *(const f32x4*)(partials + ((size_t)c * 64 + bh) * 4096 + off);
      s += p;
    }
    *(f32x4*)&dl[off] = s;
  }
#pragma unroll
  for (int i = 0; i < 16; ++i) {
    int idx4 = i * 256 + t;           // float4 index into [64][256]
    int d = idx4 >> 6, c4 = idx4 & 63;
    *(f32x4*)&wqls[d * 256 + c4 * 4] =
        *(const f32x4*)(wqkv + (size_t)(h * 64 + d) * 256 + c4 * 4);
  }
  __syncthreads();
  const int k = t;
  const float scale = 1.0f / 8192.0f;
  float res[64];
  for (int e = 0; e < 64; ++e) {
    float s = 0.f;
#pragma unroll
    for (int d = 0; d < 64; ++d) s += dl[d * 64 + e] * wqls[d * 256 + k];
    res[e] = s * scale;
  }
  unsigned short* dst = tmpT + (size_t)b * 131072 + (size_t)k * 512 + h * 64;
#pragma unroll
  for (int e8 = 0; e8 < 8; ++e8) {
    ushort8_t o;
#pragma unroll
    for (int j = 0; j < 8; ++j) o[j] = f2bf(res[e8 * 8 + j]);
    *(ushort8_t*)(dst + e8 * 8) = o;
  }
}

// ---------------- kernel 5: P^T[b] = woutb(256o x 512he) @ tmpT[b](256k x 512he)
// writes P in gemm2 B-fragment order. Grid 32 = b*4 + (oq*2+kq); 256 thr, 4 waves 2x2.
__global__ __launch_bounds__(256) void k_pmat(const unsigned short* __restrict__ woutb,
                                              const unsigned short* __restrict__ tmpT,
                                              unsigned short* __restrict__ pswz) {
  const int bid = blockIdx.x;
  const int b = bid >> 2, oq = (bid >> 1) & 1, kq = bid & 1;
  const int t = threadIdx.x, w = t >> 6, lane = t & 63, lr = lane & 15, lg = lane >> 4;
  const int wr = w >> 1, wc = w & 1;
  const int ob = oq * 128 + wr * 64, kb = kq * 128 + wc * 64;
  const unsigned short* tb = tmpT + (size_t)b * 131072;

  f32x4 acc[4][4];
#pragma unroll
  for (int mb = 0; mb < 4; ++mb)
#pragma unroll
    for (int nb = 0; nb < 4; ++nb) acc[mb][nb] = f32x4{0.f, 0.f, 0.f, 0.f};

  for (int ks = 0; ks < 16; ++ks) {
    bf16x8 a[4], bb[4];
#pragma unroll
    for (int mb = 0; mb < 4; ++mb)
      a[mb] = *(const bf16x8*)(woutb + (size_t)(ob + mb * 16 + lr) * 512 + ks * 32 + lg * 8);
#pragma unroll
    for (int nb = 0; nb < 4; ++nb)
      bb[nb] = *(const bf16x8*)(tb + (size_t)(kb + nb * 16 + lr) * 512 + ks * 32 + lg * 8);
#pragma unroll
    for (int mb = 0; mb < 4; ++mb)
#pragma unroll
      for (int nb = 0; nb < 4; ++nb) acc[mb][nb] = MFMA16(a[mb], bb[nb], acc[mb][nb]);
  }

  // write in gemm2 fragment order: addr = ((k32*16 + (o>>4))*64 + (o&15) + ((k>>3)&3)*16)*8 + (k&7)
  unsigned short* pb = pswz + (size_t)b * 65536;
#pragma unroll
  for (int mb = 0; mb < 4; ++mb)
#pragma unroll
    for (int nb = 0; nb < 4; ++nb)
#pragma unroll
      for (int rg = 0; rg < 4; ++rg) {
        int o = ob + mb * 16 + lg * 4 + rg;
        int k = kb + nb * 16 + lr;
        pb[(((k >> 5) * 16 + (o >> 4)) * 64 + (o & 15) + ((k >> 3) & 3) * 16) * 8 + (k & 7)] =
            f2bf(acc[mb][nb][rg]);
      }
}

// ---------------- kernel 6: out[b] = xb[b] @ P[b] + b_out  (M=8192, N=256, K=256)
__global__ __launch_bounds__(512) void k_gemm2(const unsigned short* __restrict__ xb,
                                               const unsigned short* __restrict__ pswz,
                                               const float* __restrict__ bout,
                                               float* __restrict__ out) {
  __shared__ unsigned short As[2][128 * 64];  // 32 KB
  const int b = blockIdx.x >> 6, mt = blockIdx.x & 63;
  const long m0 = (long)mt * 128;
  const int t = threadIdx.x, w = t >> 6, lane = t & 63, lr = lane & 15, lg = lane >> 4;
  const int wr = w >> 2, wc = w & 3;  // wave: 64 rows x 64 cols
  const unsigned short* qb = xb + ((size_t)b * 8192 + m0) * 256;
  const unsigned short* Mb = pswz + (size_t)b * 65536;
  const int srl = lane >> 3, sc = lane & 7;

#pragma unroll
  for (int i = 0; i < 2; ++i) {
    const int row = (i * 8 + w) * 8 + srl;  // 0..127
    gld_lds16(qb + (size_t)row * 256 + ((sc ^ (row & 7)) << 3),
              &As[0][(i * 8 + w) * 512]);
  }
  __syncthreads();

  f32x4 acc[4][4];
#pragma unroll
  for (int mb = 0; mb < 4; ++mb)
#pragma unroll
    for (int nb = 0; nb < 4; ++nb) acc[mb][nb] = f32x4{0.f, 0.f, 0.f, 0.f};

  for (int ks = 0; ks < 4; ++ks) {
    const int cur = ks & 1, nxt = cur ^ 1;
    if (ks < 3) {
      const int k0 = (ks + 1) * 64;
#pragma unroll
      for (int i = 0; i < 2; ++i) {
        const int row = (i * 8 + w) * 8 + srl;
        gld_lds16(qb + (size_t)row * 256 + k0 + ((sc ^ (row & 7)) << 3),
                  &As[nxt][(i * 8 + w) * 512]);
      }
    }
    bf16x8 a[4][2], bfr[2][4];
#pragma unroll
    for (int mb = 0; mb < 4; ++mb) {
      const int R = wr * 64 + mb * 16 + lr;
#pragma unroll
      for (int kh = 0; kh < 2; ++kh)
        a[mb][kh] = *(const bf16x8*)&As[cur][R * 64 + ((((kh << 2) + lg) ^ (R & 7)) << 3)];
    }
#pragma unroll
    for (int kh = 0; kh < 2; ++kh)
#pragma unroll
      for (int nb = 0; nb < 4; ++nb)
        bfr[kh][nb] = *(const bf16x8*)(Mb + ((((size_t)ks * 2 + kh) * 16 + wc * 4 + nb) * 64 + lane) * 8);
#pragma unroll
    for (int mb = 0; mb < 4; ++mb)
#pragma unroll
      for (int nb = 0; nb < 4; ++nb)
#pragma unroll
        for (int kh = 0; kh < 2; ++kh)
          acc[mb][nb] = MFMA16(a[mb][kh], bfr[kh][nb], acc[mb][nb]);
    __syncthreads();
  }

  float bo[4];
#pragma unroll
  for (int nb = 0; nb < 4; ++nb) bo[nb] = bout[wc * 64 + nb * 16 + lr];
  float* ob = out + ((size_t)b * 8192 + m0) * 256;
#pragma unroll
  for (int mb = 0; mb < 4; ++mb)
#pragma unroll
    for (int nb = 0; nb < 4; ++nb)
#pragma unroll
      for (int rg = 0; rg < 4; ++rg) {
        int row = wr * 64 + mb * 16 + lg * 4 + rg;
        int c = wc * 64 + nb * 16 + lr;
        ob[(size_t)row * 256 + c] = acc[mb][nb][rg] + bo[nb];
      }
}

extern "C" void kernel_launch(void* const* d_in, const int* in_sizes, int n_in,
                              void* d_out, int out_size, void* d_ws, size_t ws_size,
                              hipStream_t stream) {
  const float* x    = (const float*)d_in[0];  // [8,8192,256]
  const float* wqkv = (const float*)d_in[1];  // [1536,256]
  const float* wout = (const float*)d_in[2];  // [256,512]
  const float* bout = (const float*)d_in[3];  // [256]
  float* out = (float*)d_out;                 // [8,8192,256] f32

  char* ws = (char*)d_ws;
  unsigned short* kvb = (unsigned short*)ws;                  // 65536*1024 bf16 = 128 MB
  size_t off = (size_t)65536 * 1024 * 2;
  unsigned short* xb = (unsigned short*)(ws + off);           // 65536*256 bf16 = 32 MB
  off += (size_t)65536 * 256 * 2;
  unsigned short* wqb = (unsigned short*)(ws + off);          // 1536*256 bf16
  off += (size_t)1536 * 256 * 2;
  unsigned short* woutb = (unsigned short*)(ws + off);        // 256*512 bf16
  off += (size_t)256 * 512 * 2;
  float* partials = (float*)(ws + off);                       // 8*64*4096 f32 = 8 MB
  off += (size_t)8 * 64 * 4096 * 4;
  unsigned short* tmpT = (unsigned short*)(ws + off);         // 8*256*512 bf16 = 2 MB
  off += (size_t)8 * 131072 * 2;
  unsigned short* pswz = (unsigned short*)(ws + off);         // 8*256*256 bf16 = 1 MB
  off += (size_t)8 * 65536 * 2;

  k_convx<<<16384, 256, 0, stream>>>(x, xb);
  k_convw<<<384, 256, 0, stream>>>(wqkv, wqb);
  k_convo<<<128, 256, 0, stream>>>(wout, woutb);
  k_gemm1<<<1024, 512, 0, stream>>>(xb, wqb, kvb);
  dim3 gd(64, 8);
  k_dots<<<gd, 256, 0, stream>>>(kvb, partials);
  k_mmat<<<64, 256, 0, stream>>>(partials, wqkv, tmpT);
  k_pmat<<<32, 256, 0, stream>>>(woutb, tmpT, pswz);
  k_gemm2<<<512, 512, 0, stream>>>(xb, pswz, bout, out);
}

// Round 6
// 169.759 us; speedup vs baseline: 1.9003x; 1.0831x over previous
//
#include <hip/hip_runtime.h>
#include <hip/hip_bf16.h>
#include <stdint.h>

typedef __attribute__((ext_vector_type(8))) __bf16 bf16x8;
typedef __attribute__((ext_vector_type(8))) unsigned short ushort8_t;
typedef __attribute__((ext_vector_type(4))) unsigned short ushort4_t;
typedef __attribute__((ext_vector_type(4))) float f32x4;

#define MFMA16(a, b, c) __builtin_amdgcn_mfma_f32_16x16x32_bf16((a), (b), (c), 0, 0, 0)

static __device__ __forceinline__ unsigned short f2bf(float f) {
  union { float f; unsigned u; } v; v.f = f;
  unsigned r = v.u + 0x7fffu + ((v.u >> 16) & 1u);  // RNE
  return (unsigned short)(r >> 16);
}
static __device__ __forceinline__ float bf2f(unsigned short u) {
  union { unsigned u; float f; } v; v.u = ((unsigned)u) << 16; return v.f;
}

static __device__ __forceinline__ void gld_lds16(const void* g, void* l) {
  __builtin_amdgcn_global_load_lds((const __attribute__((address_space(1))) void*)g,
                                   (__attribute__((address_space(3))) void*)l, 16, 0, 0);
}

// ---------------- kernel 0a: convert x f32 -> bf16 (row-major [65536][256])
__global__ __launch_bounds__(256) void k_convx(const float* __restrict__ x,
                                               unsigned short* __restrict__ xb) {
  size_t i = ((size_t)blockIdx.x * 256 + threadIdx.x) * 4;  // 16384 blocks exact
  float4 v = *(const float4*)(x + i);
  ushort4_t o = { f2bf(v.x), f2bf(v.y), f2bf(v.z), f2bf(v.w) };
  *(ushort4_t*)(xb + i) = o;
}

// ---------------- kernel 0b: convert w_qkv f32 -> bf16 ([1536][256])
__global__ void k_convw(const float* __restrict__ w, unsigned short* __restrict__ wb) {
  int i = (blockIdx.x * 256 + threadIdx.x) * 4;  // 384 blocks
  float4 v = *(const float4*)(w + i);
  ushort4_t o = { f2bf(v.x), f2bf(v.y), f2bf(v.z), f2bf(v.w) };
  *(ushort4_t*)(wb + i) = o;
}

// ---------------- kernel 0c: convert w_out f32 -> bf16 ([256][512])
__global__ void k_convo(const float* __restrict__ w, unsigned short* __restrict__ wb) {
  int i = (blockIdx.x * 256 + threadIdx.x) * 4;  // 128 blocks
  float4 v = *(const float4*)(w + i);
  ushort4_t o = { f2bf(v.x), f2bf(v.y), f2bf(v.z), f2bf(v.w) };
  *(ushort4_t*)(wb + i) = o;
}

// ---------------- kernel 1: FUSED  K/V projection + instance-norm + dots partial.
// Grid 2048: block = 256 token-rows x one head h: computes K_h,V_h (256x128, K=256),
// norms rows in-register, LDS-transposes ([64][72] layout), MFMA K^T V -> 64x64 partial.
__global__ __launch_bounds__(512) void k_fused(const unsigned short* __restrict__ xb,
                                               const unsigned short* __restrict__ wqb,
                                               float* __restrict__ partials) {
  __shared__ __align__(16) char smem[98304];
  unsigned short* As = (unsigned short*)smem;            // [2][256*64]  (64 KB)
  unsigned short* Bs = (unsigned short*)(smem + 65536);  // [2][128*64]  (32 KB)
  unsigned short* kt = (unsigned short*)smem;            // overlay: [4][64*72] (36 KB)
  unsigned short* vt = (unsigned short*)(smem + 36864);  // overlay: [4][64*72] (36 KB)

  const int t = threadIdx.x;
  const int w = t >> 6, lane = t & 63, lr = lane & 15, lg = lane >> 4;
  const int wr = w >> 1, wc = w & 1;  // wave: rows [wr*64,+64), wc=0 -> K_h, wc=1 -> V_h

  // XCD-chunked swizzle: XCD x gets m-tiles [x*32,(x+1)*32) for all 8 heads (A reuse in L2)
  const int id = blockIdx.x;
  const int nid = (id & 7) * 256 + (id >> 3);
  const int mt = nid >> 3, h = nid & 7;
  const long m0 = (long)mt * 256;

  const unsigned short* bk = wqb + (size_t)(512 + h * 64) * 256;   // K_h rows [64][256]
  const unsigned short* bv = wqb + (size_t)(1024 + h * 64) * 256;  // V_h rows [64][256]

  const int srl = t >> 3, sc = t & 7;  // staging: 64 rows-per-iter, 8 chunks/row
  const int swz = (sc ^ (srl & 7)) << 3;

  // ---- prologue: stage K-tile 0 into buf 0
#pragma unroll
  for (int i = 0; i < 4; ++i)
    gld_lds16(xb + (size_t)(m0 + i * 64 + srl) * 256 + swz, &As[i * 4096 + t * 8]);
  gld_lds16(bk + (size_t)srl * 256 + swz, &Bs[t * 8]);
  gld_lds16(bv + (size_t)srl * 256 + swz, &Bs[4096 + t * 8]);
  __syncthreads();

  f32x4 acc[4][4];
#pragma unroll
  for (int mb = 0; mb < 4; ++mb)
#pragma unroll
    for (int nb = 0; nb < 4; ++nb) acc[mb][nb] = f32x4{0.f, 0.f, 0.f, 0.f};

  for (int ks = 0; ks < 4; ++ks) {
    const int cur = ks & 1, nxt = cur ^ 1;
    if (ks < 3) {
      const int k0 = (ks + 1) * 64;
#pragma unroll
      for (int i = 0; i < 4; ++i)
        gld_lds16(xb + (size_t)(m0 + i * 64 + srl) * 256 + k0 + swz,
                  &As[nxt * 16384 + i * 4096 + t * 8]);
      gld_lds16(bk + (size_t)srl * 256 + k0 + swz, &Bs[nxt * 8192 + t * 8]);
      gld_lds16(bv + (size_t)srl * 256 + k0 + swz, &Bs[nxt * 8192 + 4096 + t * 8]);
    }
    bf16x8 a[4][2], b[4][2];
#pragma unroll
    for (int mb = 0; mb < 4; ++mb) {
      const int R = wr * 64 + mb * 16 + lr;
#pragma unroll
      for (int kh = 0; kh < 2; ++kh)
        a[mb][kh] = *(const bf16x8*)&As[cur * 16384 + R * 64 + ((((kh << 2) + lg) ^ (R & 7)) << 3)];
    }
#pragma unroll
    for (int nb = 0; nb < 4; ++nb) {
      const int E = wc * 64 + nb * 16 + lr;
#pragma unroll
      for (int kh = 0; kh < 2; ++kh)
        b[nb][kh] = *(const bf16x8*)&Bs[cur * 8192 + E * 64 + ((((kh << 2) + lg) ^ (E & 7)) << 3)];
    }
#pragma unroll
    for (int mb = 0; mb < 4; ++mb)
#pragma unroll
      for (int nb = 0; nb < 4; ++nb)
#pragma unroll
        for (int kh = 0; kh < 2; ++kh)
          acc[mb][nb] = MFMA16(a[mb][kh], b[nb][kh], acc[mb][nb]);
    __syncthreads();
  }

  // ---- instance-norm in-register (per row over 64 d), write to [cn][d][72] transpose LDS
  unsigned short* dst = (wc == 0 ? kt : vt) + wr * 4608;
#pragma unroll
  for (int mb = 0; mb < 4; ++mb) {
#pragma unroll
    for (int rg = 0; rg < 4; ++rg) {
      float s1 = acc[mb][0][rg] + acc[mb][1][rg] + acc[mb][2][rg] + acc[mb][3][rg];
      float s2 = acc[mb][0][rg] * acc[mb][0][rg] + acc[mb][1][rg] * acc[mb][1][rg] +
                 acc[mb][2][rg] * acc[mb][2][rg] + acc[mb][3][rg] * acc[mb][3][rg];
      s1 += __shfl_xor(s1, 1); s2 += __shfl_xor(s2, 1);
      s1 += __shfl_xor(s1, 2); s2 += __shfl_xor(s2, 2);
      s1 += __shfl_xor(s1, 4); s2 += __shfl_xor(s2, 4);
      s1 += __shfl_xor(s1, 8); s2 += __shfl_xor(s2, 8);
      const float mean = s1 * (1.f / 64.f);
      const float rs = rsqrtf(s2 * (1.f / 64.f) - mean * mean + 1e-5f);
      const int nn = mb * 16 + lg * 4 + rg;
#pragma unroll
      for (int nb = 0; nb < 4; ++nb)
        dst[(nb * 16 + lr) * 72 + nn] = f2bf((acc[mb][nb][rg] - mean) * rs);
    }
  }
  __syncthreads();

  // ---- dots: D[d,e] = sum_n K^[n,d] V^[n,e]; wave w: d-block w>>1, e-pair w&1
  const int dblk = w >> 1, ep = w & 1;
  f32x4 acc2[2] = {f32x4{0.f, 0.f, 0.f, 0.f}, f32x4{0.f, 0.f, 0.f, 0.f}};
#pragma unroll
  for (int cn = 0; cn < 4; ++cn) {
#pragma unroll
    for (int ns = 0; ns < 64; ns += 32) {
      bf16x8 af = *(const bf16x8*)&kt[cn * 4608 + (dblk * 16 + lr) * 72 + ns + lg * 8];
#pragma unroll
      for (int e = 0; e < 2; ++e) {
        bf16x8 bvf = *(const bf16x8*)&vt[cn * 4608 + ((ep * 2 + e) * 16 + lr) * 72 + ns + lg * 8];
        acc2[e] = MFMA16(af, bvf, acc2[e]);
      }
    }
  }
  float* pb = partials + ((size_t)mt * 8 + h) * 4096;
#pragma unroll
  for (int e = 0; e < 2; ++e)
#pragma unroll
    for (int rg = 0; rg < 4; ++rg) {
      int d = dblk * 16 + lg * 4 + rg;
      int eo = (ep * 2 + e) * 16 + lr;
      pb[d * 64 + eo] = acc2[e][rg];
    }
}

// ---------------- kernel 4: tmpT[b][k][h*64+e] = (1/N) * sum_d dots_h[d,e] * Wq[h*64+d, k]
// One block per bh; reduces 32 m-tile partial chunks. f32 math, bf16 store.
__global__ __launch_bounds__(256) void k_mmat(const float* __restrict__ partials,
                                              const float* __restrict__ wqkv,
                                              unsigned short* __restrict__ tmpT) {
  __shared__ float dl[4096];        // dots [d][e]
  __shared__ float wqls[64 * 256];  // Wq rows h*64+d: [d][k]
  const int bh = blockIdx.x, b = bh >> 3, h = bh & 7;
  const int t = threadIdx.x;
#pragma unroll
  for (int i = 0; i < 4; ++i) {
    int off = t * 16 + i * 4;
    f32x4 s = {0.f, 0.f, 0.f, 0.f};
    for (int c = 0; c < 32; ++c) {
      f32x4 p = *(const f32x4*)(partials + ((size_t)(b * 32 + c) * 8 + h) * 4096 + off);
      s += p;
    }
    *(f32x4*)&dl[off] = s;
  }
#pragma unroll
  for (int i = 0; i < 16; ++i) {
    int idx4 = i * 256 + t;           // float4 index into [64][256]
    int d = idx4 >> 6, c4 = idx4 & 63;
    *(f32x4*)&wqls[d * 256 + c4 * 4] =
        *(const f32x4*)(wqkv + (size_t)(h * 64 + d) * 256 + c4 * 4);
  }
  __syncthreads();
  const int k = t;
  const float scale = 1.0f / 8192.0f;
  float res[64];
  for (int e = 0; e < 64; ++e) {
    float s = 0.f;
#pragma unroll
    for (int d = 0; d < 64; ++d) s += dl[d * 64 + e] * wqls[d * 256 + k];
    res[e] = s * scale;
  }
  unsigned short* dstp = tmpT + (size_t)b * 131072 + (size_t)k * 512 + h * 64;
#pragma unroll
  for (int e8 = 0; e8 < 8; ++e8) {
    ushort8_t o;
#pragma unroll
    for (int j = 0; j < 8; ++j) o[j] = f2bf(res[e8 * 8 + j]);
    *(ushort8_t*)(dstp + e8 * 8) = o;
  }
}

// ---------------- kernel 5: P^T[b] = woutb(256o x 512he) @ tmpT[b](256k x 512he)
// writes P in gemm2 B-fragment order. Grid 32 = b*4 + (oq*2+kq); 256 thr, 4 waves 2x2.
__global__ __launch_bounds__(256) void k_pmat(const unsigned short* __restrict__ woutb,
                                              const unsigned short* __restrict__ tmpT,
                                              unsigned short* __restrict__ pswz) {
  const int bid = blockIdx.x;
  const int b = bid >> 2, oq = (bid >> 1) & 1, kq = bid & 1;
  const int t = threadIdx.x, w = t >> 6, lane = t & 63, lr = lane & 15, lg = lane >> 4;
  const int wr = w >> 1, wc = w & 1;
  const int ob = oq * 128 + wr * 64, kb = kq * 128 + wc * 64;
  const unsigned short* tb = tmpT + (size_t)b * 131072;

  f32x4 acc[4][4];
#pragma unroll
  for (int mb = 0; mb < 4; ++mb)
#pragma unroll
    for (int nb = 0; nb < 4; ++nb) acc[mb][nb] = f32x4{0.f, 0.f, 0.f, 0.f};

  for (int ks = 0; ks < 16; ++ks) {
    bf16x8 a[4], bb[4];
#pragma unroll
    for (int mb = 0; mb < 4; ++mb)
      a[mb] = *(const bf16x8*)(woutb + (size_t)(ob + mb * 16 + lr) * 512 + ks * 32 + lg * 8);
#pragma unroll
    for (int nb = 0; nb < 4; ++nb)
      bb[nb] = *(const bf16x8*)(tb + (size_t)(kb + nb * 16 + lr) * 512 + ks * 32 + lg * 8);
#pragma unroll
    for (int mb = 0; mb < 4; ++mb)
#pragma unroll
      for (int nb = 0; nb < 4; ++nb) acc[mb][nb] = MFMA16(a[mb], bb[nb], acc[mb][nb]);
  }

  // write in gemm2 fragment order: addr = ((k32*16 + (o>>4))*64 + (o&15) + ((k>>3)&3)*16)*8 + (k&7)
  unsigned short* pb = pswz + (size_t)b * 65536;
#pragma unroll
  for (int mb = 0; mb < 4; ++mb)
#pragma unroll
    for (int nb = 0; nb < 4; ++nb)
#pragma unroll
      for (int rg = 0; rg < 4; ++rg) {
        int o = ob + mb * 16 + lg * 4 + rg;
        int k = kb + nb * 16 + lr;
        pb[(((k >> 5) * 16 + (o >> 4)) * 64 + (o & 15) + ((k >> 3) & 3) * 16) * 8 + (k & 7)] =
            f2bf(acc[mb][nb][rg]);
      }
}

// ---------------- kernel 6: out[b] = xb[b] @ P[b] + b_out  (M=8192, N=256, K=256)
__global__ __launch_bounds__(512) void k_gemm2(const unsigned short* __restrict__ xb,
                                               const unsigned short* __restrict__ pswz,
                                               const float* __restrict__ bout,
                                               float* __restrict__ out) {
  __shared__ unsigned short As[2][128 * 64];  // 32 KB
  const int b = blockIdx.x >> 6, mt = blockIdx.x & 63;
  const long m0 = (long)mt * 128;
  const int t = threadIdx.x, w = t >> 6, lane = t & 63, lr = lane & 15, lg = lane >> 4;
  const int wr = w >> 2, wc = w & 3;  // wave: 64 rows x 64 cols
  const unsigned short* qb = xb + ((size_t)b * 8192 + m0) * 256;
  const unsigned short* Mb = pswz + (size_t)b * 65536;
  const int srl = lane >> 3, sc = lane & 7;

#pragma unroll
  for (int i = 0; i < 2; ++i) {
    const int row = (i * 8 + w) * 8 + srl;  // 0..127
    gld_lds16(qb + (size_t)row * 256 + ((sc ^ (row & 7)) << 3),
              &As[0][(i * 8 + w) * 512]);
  }
  __syncthreads();

  f32x4 acc[4][4];
#pragma unroll
  for (int mb = 0; mb < 4; ++mb)
#pragma unroll
    for (int nb = 0; nb < 4; ++nb) acc[mb][nb] = f32x4{0.f, 0.f, 0.f, 0.f};

  for (int ks = 0; ks < 4; ++ks) {
    const int cur = ks & 1, nxt = cur ^ 1;
    if (ks < 3) {
      const int k0 = (ks + 1) * 64;
#pragma unroll
      for (int i = 0; i < 2; ++i) {
        const int row = (i * 8 + w) * 8 + srl;
        gld_lds16(qb + (size_t)row * 256 + k0 + ((sc ^ (row & 7)) << 3),
                  &As[nxt][(i * 8 + w) * 512]);
      }
    }
    bf16x8 a[4][2], bfr[2][4];
#pragma unroll
    for (int mb = 0; mb < 4; ++mb) {
      const int R = wr * 64 + mb * 16 + lr;
#pragma unroll
      for (int kh = 0; kh < 2; ++kh)
        a[mb][kh] = *(const bf16x8*)&As[cur][R * 64 + ((((kh << 2) + lg) ^ (R & 7)) << 3)];
    }
#pragma unroll
    for (int kh = 0; kh < 2; ++kh)
#pragma unroll
      for (int nb = 0; nb < 4; ++nb)
        bfr[kh][nb] = *(const bf16x8*)(Mb + ((((size_t)ks * 2 + kh) * 16 + wc * 4 + nb) * 64 + lane) * 8);
#pragma unroll
    for (int mb = 0; mb < 4; ++mb)
#pragma unroll
      for (int nb = 0; nb < 4; ++nb)
#pragma unroll
        for (int kh = 0; kh < 2; ++kh)
          acc[mb][nb] = MFMA16(a[mb][kh], bfr[kh][nb], acc[mb][nb]);
    __syncthreads();
  }

  float bo[4];
#pragma unroll
  for (int nb = 0; nb < 4; ++nb) bo[nb] = bout[wc * 64 + nb * 16 + lr];
  float* ob = out + ((size_t)b * 8192 + m0) * 256;
#pragma unroll
  for (int mb = 0; mb < 4; ++mb)
#pragma unroll
    for (int nb = 0; nb < 4; ++nb)
#pragma unroll
      for (int rg = 0; rg < 4; ++rg) {
        int row = wr * 64 + mb * 16 + lg * 4 + rg;
        int c = wc * 64 + nb * 16 + lr;
        ob[(size_t)row * 256 + c] = acc[mb][nb][rg] + bo[nb];
      }
}

extern "C" void kernel_launch(void* const* d_in, const int* in_sizes, int n_in,
                              void* d_out, int out_size, void* d_ws, size_t ws_size,
                              hipStream_t stream) {
  const float* x    = (const float*)d_in[0];  // [8,8192,256]
  const float* wqkv = (const float*)d_in[1];  // [1536,256]
  const float* wout = (const float*)d_in[2];  // [256,512]
  const float* bout = (const float*)d_in[3];  // [256]
  float* out = (float*)d_out;                 // [8,8192,256] f32

  char* ws = (char*)d_ws;
  unsigned short* xb = (unsigned short*)ws;                   // 65536*256 bf16 = 32 MB
  size_t off = (size_t)65536 * 256 * 2;
  unsigned short* wqb = (unsigned short*)(ws + off);          // 1536*256 bf16
  off += (size_t)1536 * 256 * 2;
  unsigned short* woutb = (unsigned short*)(ws + off);        // 256*512 bf16
  off += (size_t)256 * 512 * 2;
  float* partials = (float*)(ws + off);                       // 2048*4096 f32 = 32 MB
  off += (size_t)2048 * 4096 * 4;
  unsigned short* tmpT = (unsigned short*)(ws + off);         // 8*256*512 bf16 = 2 MB
  off += (size_t)8 * 131072 * 2;
  unsigned short* pswz = (unsigned short*)(ws + off);         // 8*256*256 bf16 = 1 MB
  off += (size_t)8 * 65536 * 2;

  k_convx<<<16384, 256, 0, stream>>>(x, xb);
  k_convw<<<384, 256, 0, stream>>>(wqkv, wqb);
  k_convo<<<128, 256, 0, stream>>>(wout, woutb);
  k_fused<<<2048, 512, 0, stream>>>(xb, wqb, partials);
  k_mmat<<<64, 256, 0, stream>>>(partials, wqkv, tmpT);
  k_pmat<<<32, 256, 0, stream>>>(woutb, tmpT, pswz);
  k_gemm2<<<512, 512, 0, stream>>>(xb, pswz, bout, out);
}